// Round 1
// baseline (1375.398 us; speedup 1.0000x reference)
//
#include <hip/hip_runtime.h>

#define N_NODES 50000
#define E_EDGES 1600000
#define ETOT    (E_EDGES + N_NODES)
#define DIN  128
#define DOUT 128
#define NH   4
#define HD   32

// ---------------- K1: h = x @ W^T  (fp32, LDS-tiled) ----------------
// block = 512 threads, TILE_M = 64 nodes. Wt[k][o] transposed in LDS with
// +1 pad (row 129) so transpose-write and column-read are conflict-free.
__global__ __launch_bounds__(512) void gemm_kernel(
    const float* __restrict__ x, const float* __restrict__ W,
    float* __restrict__ h) {
  __shared__ float Wt[DIN][DOUT + 1];   // 66,048 B
  __shared__ float xt[64][DIN];         // 32,768 B
  const int tid = threadIdx.x;
  const int m0 = blockIdx.x * 64;

  // stage W transposed: read W[o][k] coalesced, write Wt[k][o]
  for (int i = tid; i < DIN * DOUT; i += 512) {
    int o = i >> 7, k = i & 127;
    Wt[k][o] = W[i];
  }
  // stage x tile (guard tail block)
  for (int i = tid; i < 64 * DIN; i += 512) {
    int n = m0 + (i >> 7);
    xt[i >> 7][i & 127] = (n < N_NODES) ? x[(size_t)n * DIN + (i & 127)] : 0.f;
  }
  __syncthreads();

  const int g = tid >> 6;   // wave id: nodes g*8 .. g*8+7
  const int l = tid & 63;   // output cols l and l+64
  float acc0[8], acc1[8];
#pragma unroll
  for (int i = 0; i < 8; i++) { acc0[i] = 0.f; acc1[i] = 0.f; }

  for (int k = 0; k < DIN; k += 4) {
    float w00 = Wt[k][l],      w01 = Wt[k+1][l],      w02 = Wt[k+2][l],      w03 = Wt[k+3][l];
    float w10 = Wt[k][l+64],   w11 = Wt[k+1][l+64],   w12 = Wt[k+2][l+64],   w13 = Wt[k+3][l+64];
#pragma unroll
    for (int i = 0; i < 8; i++) {
      const float4 xv = *(const float4*)&xt[g*8 + i][k];
      acc0[i] = fmaf(xv.x, w00, acc0[i]);
      acc0[i] = fmaf(xv.y, w01, acc0[i]);
      acc0[i] = fmaf(xv.z, w02, acc0[i]);
      acc0[i] = fmaf(xv.w, w03, acc0[i]);
      acc1[i] = fmaf(xv.x, w10, acc1[i]);
      acc1[i] = fmaf(xv.y, w11, acc1[i]);
      acc1[i] = fmaf(xv.z, w12, acc1[i]);
      acc1[i] = fmaf(xv.w, w13, acc1[i]);
    }
  }
#pragma unroll
  for (int i = 0; i < 8; i++) {
    int n = m0 + g * 8 + i;
    if (n < N_NODES) {
      h[(size_t)n * DOUT + l]      = acc0[i];
      h[(size_t)n * DOUT + l + 64] = acc1[i];
    }
  }
}

// ---------------- K2: per-node attention logits ----------------
__global__ __launch_bounds__(256) void att_logits_kernel(
    const float* __restrict__ h, const float* __restrict__ att_src,
    const float* __restrict__ att_dst, float* __restrict__ a_src,
    float* __restrict__ a_dst) {
  int t = blockIdx.x * 256 + threadIdx.x;
  if (t >= N_NODES * NH) return;
  int n = t >> 2, hd = t & 3;
  const float* hp = h + (size_t)n * DOUT + hd * HD;
  const float* as = att_src + hd * HD;
  const float* ad = att_dst + hd * HD;
  float s1 = 0.f, s2 = 0.f;
#pragma unroll
  for (int j = 0; j < HD; j += 4) {
    float4 hv = *(const float4*)(hp + j);
    float4 av = *(const float4*)(as + j);
    float4 dv = *(const float4*)(ad + j);
    s1 += hv.x * av.x + hv.y * av.y + hv.z * av.z + hv.w * av.w;
    s2 += hv.x * dv.x + hv.y * dv.y + hv.z * dv.z + hv.w * dv.w;
  }
  a_src[t] = s1;
  a_dst[t] = s2;
}

// sortable-uint encoding for float atomicMax (works for negatives)
__device__ __forceinline__ unsigned enc_f(float f) {
  unsigned u = __float_as_uint(f);
  return (u & 0x80000000u) ? ~u : (u | 0x80000000u);
}
__device__ __forceinline__ float dec_f(unsigned u) {
  unsigned v = (u & 0x80000000u) ? (u & 0x7FFFFFFFu) : ~u;
  return __uint_as_float(v);
}

// ---------------- K3: per-edge alpha + segment max ----------------
__global__ __launch_bounds__(256) void alpha_max_kernel(
    const int* __restrict__ ei, const float* __restrict__ a_src,
    const float* __restrict__ a_dst, float* __restrict__ alpha,
    unsigned* __restrict__ m_enc) {
  int e = blockIdx.x * 256 + threadIdx.x;
  if (e >= ETOT) return;
  int si, di;
  if (e < E_EDGES) { si = ei[e]; di = ei[E_EDGES + e]; }
  else             { si = e - E_EDGES; di = si; }
  float4 as = *(const float4*)(a_src + (size_t)si * NH);
  float4 ad = *(const float4*)(a_dst + (size_t)di * NH);
  float4 v;
  v.x = as.x + ad.x; v.y = as.y + ad.y; v.z = as.z + ad.z; v.w = as.w + ad.w;
  v.x = v.x > 0.f ? v.x : 0.2f * v.x;
  v.y = v.y > 0.f ? v.y : 0.2f * v.y;
  v.z = v.z > 0.f ? v.z : 0.2f * v.z;
  v.w = v.w > 0.f ? v.w : 0.2f * v.w;
  *(float4*)(alpha + (size_t)e * NH) = v;
  atomicMax(&m_enc[di * NH + 0], enc_f(v.x));
  atomicMax(&m_enc[di * NH + 1], enc_f(v.y));
  atomicMax(&m_enc[di * NH + 2], enc_f(v.z));
  atomicMax(&m_enc[di * NH + 3], enc_f(v.w));
}

// ---------------- K4: e = exp(alpha - m[dst]); s += e ----------------
__global__ __launch_bounds__(256) void exp_sum_kernel(
    const int* __restrict__ ei, const unsigned* __restrict__ m_enc,
    float* __restrict__ alpha, float* __restrict__ s) {
  int e = blockIdx.x * 256 + threadIdx.x;
  if (e >= ETOT) return;
  int di = (e < E_EDGES) ? ei[E_EDGES + e] : (e - E_EDGES);
  float4 v = *(const float4*)(alpha + (size_t)e * NH);
  float m0 = dec_f(m_enc[di * NH + 0]);
  float m1 = dec_f(m_enc[di * NH + 1]);
  float m2 = dec_f(m_enc[di * NH + 2]);
  float m3 = dec_f(m_enc[di * NH + 3]);
  float4 ev;
  ev.x = __expf(v.x - m0);
  ev.y = __expf(v.y - m1);
  ev.z = __expf(v.z - m2);
  ev.w = __expf(v.w - m3);
  *(float4*)(alpha + (size_t)e * NH) = ev;
  atomicAdd(&s[di * NH + 0], ev.x);
  atomicAdd(&s[di * NH + 1], ev.y);
  atomicAdd(&s[di * NH + 2], ev.z);
  atomicAdd(&s[di * NH + 3], ev.w);
}

// ---------------- K5: weighted scatter-add aggregation ----------------
// 128 threads per edge (one per output component), 2 edges per block.
__global__ __launch_bounds__(256) void aggregate_kernel(
    const int* __restrict__ ei, const float* __restrict__ h,
    const float* __restrict__ e_buf, const float* __restrict__ s,
    float* __restrict__ out) {
  unsigned gid = blockIdx.x * 256u + threadIdx.x;
  int e = gid >> 7;
  int c = gid & 127;
  if (e >= ETOT) return;
  int si, di;
  if (e < E_EDGES) { si = ei[e]; di = ei[E_EDGES + e]; }
  else             { si = e - E_EDGES; di = si; }
  int head = c >> 5;
  float ev = e_buf[(size_t)e * NH + head];
  float sv = s[di * NH + head];
  float w = ev / sv + 1.0f;
  atomicAdd(&out[(size_t)di * DOUT + c], h[(size_t)si * DOUT + c] * w);
}

extern "C" void kernel_launch(void* const* d_in, const int* in_sizes, int n_in,
                              void* d_out, int out_size, void* d_ws, size_t ws_size,
                              hipStream_t stream) {
  const float* x       = (const float*)d_in[0];
  const int*   ei      = (const int*)d_in[1];
  const float* W       = (const float*)d_in[2];
  const float* att_src = (const float*)d_in[3];
  const float* att_dst = (const float*)d_in[4];
  float* out = (float*)d_out;

  // workspace layout (fp32 words): h | a_src | a_dst | m_enc | s | alpha
  float* ws      = (float*)d_ws;
  float* h       = ws;
  float* a_src   = h + (size_t)N_NODES * DOUT;
  float* a_dst   = a_src + N_NODES * NH;
  unsigned* m_enc = (unsigned*)(a_dst + N_NODES * NH);
  float* s       = (float*)(m_enc + N_NODES * NH);
  float* alpha   = s + N_NODES * NH;   // Etot*4 floats

  // zero output accumulator; zero m_enc (sortable -inf) and s together
  hipMemsetAsync(d_out, 0, (size_t)out_size * sizeof(float), stream);
  hipMemsetAsync(m_enc, 0, (size_t)N_NODES * NH * 2 * sizeof(float), stream);

  gemm_kernel<<<(N_NODES + 63) / 64, 512, 0, stream>>>(x, W, h);
  att_logits_kernel<<<(N_NODES * NH + 255) / 256, 256, 0, stream>>>(
      h, att_src, att_dst, a_src, a_dst);
  alpha_max_kernel<<<(ETOT + 255) / 256, 256, 0, stream>>>(
      ei, a_src, a_dst, alpha, m_enc);
  exp_sum_kernel<<<(ETOT + 255) / 256, 256, 0, stream>>>(ei, m_enc, alpha, s);
  aggregate_kernel<<<(ETOT * 128 + 255) / 256, 256, 0, stream>>>(
      ei, h, alpha, s, out);
}

// Round 2
// 436.488 us; speedup vs baseline: 3.1511x; 3.1511x over previous
//
#include <hip/hip_runtime.h>

#define N_NODES 50000
#define E_EDGES 1600000
#define ETOT    (E_EDGES + N_NODES)
#define DIN  128
#define DOUT 128
#define NH   4
#define HD   32

// ---------------- K1: h = x @ W^T  (fp32, LDS-tiled) ----------------
__global__ __launch_bounds__(512) void gemm_kernel(
    const float* __restrict__ x, const float* __restrict__ W,
    float* __restrict__ h) {
  __shared__ float Wt[DIN][DOUT + 1];
  __shared__ float xt[64][DIN];
  const int tid = threadIdx.x;
  const int m0 = blockIdx.x * 64;

  for (int i = tid; i < DIN * DOUT; i += 512) {
    int o = i >> 7, k = i & 127;
    Wt[k][o] = W[i];
  }
  for (int i = tid; i < 64 * DIN; i += 512) {
    int n = m0 + (i >> 7);
    xt[i >> 7][i & 127] = (n < N_NODES) ? x[(size_t)n * DIN + (i & 127)] : 0.f;
  }
  __syncthreads();

  const int g = tid >> 6;
  const int l = tid & 63;
  float acc0[8], acc1[8];
#pragma unroll
  for (int i = 0; i < 8; i++) { acc0[i] = 0.f; acc1[i] = 0.f; }

  for (int k = 0; k < DIN; k += 4) {
    float w00 = Wt[k][l],    w01 = Wt[k+1][l],    w02 = Wt[k+2][l],    w03 = Wt[k+3][l];
    float w10 = Wt[k][l+64], w11 = Wt[k+1][l+64], w12 = Wt[k+2][l+64], w13 = Wt[k+3][l+64];
#pragma unroll
    for (int i = 0; i < 8; i++) {
      const float4 xv = *(const float4*)&xt[g*8 + i][k];
      acc0[i] = fmaf(xv.x, w00, acc0[i]);
      acc0[i] = fmaf(xv.y, w01, acc0[i]);
      acc0[i] = fmaf(xv.z, w02, acc0[i]);
      acc0[i] = fmaf(xv.w, w03, acc0[i]);
      acc1[i] = fmaf(xv.x, w10, acc1[i]);
      acc1[i] = fmaf(xv.y, w11, acc1[i]);
      acc1[i] = fmaf(xv.z, w12, acc1[i]);
      acc1[i] = fmaf(xv.w, w13, acc1[i]);
    }
  }
#pragma unroll
  for (int i = 0; i < 8; i++) {
    int n = m0 + g * 8 + i;
    if (n < N_NODES) {
      h[(size_t)n * DOUT + l]      = acc0[i];
      h[(size_t)n * DOUT + l + 64] = acc1[i];
    }
  }
}

// ---------------- K2: per-node attention logits ----------------
__global__ __launch_bounds__(256) void att_logits_kernel(
    const float* __restrict__ h, const float* __restrict__ att_src,
    const float* __restrict__ att_dst, float* __restrict__ a_src,
    float* __restrict__ a_dst) {
  int t = blockIdx.x * 256 + threadIdx.x;
  if (t >= N_NODES * NH) return;
  int n = t >> 2, hd = t & 3;
  const float* hp = h + (size_t)n * DOUT + hd * HD;
  const float* as = att_src + hd * HD;
  const float* ad = att_dst + hd * HD;
  float s1 = 0.f, s2 = 0.f;
#pragma unroll
  for (int j = 0; j < HD; j += 4) {
    float4 hv = *(const float4*)(hp + j);
    float4 av = *(const float4*)(as + j);
    float4 dv = *(const float4*)(ad + j);
    s1 += hv.x * av.x + hv.y * av.y + hv.z * av.z + hv.w * av.w;
    s2 += hv.x * dv.x + hv.y * dv.y + hv.z * dv.z + hv.w * dv.w;
  }
  a_src[t] = s1;
  a_dst[t] = s2;
}

// ---------------- K3: degree count ----------------
__global__ __launch_bounds__(256) void deg_kernel(
    const int* __restrict__ ei, int* __restrict__ deg) {
  int e = blockIdx.x * 256 + threadIdx.x;
  if (e >= ETOT) return;
  int di = (e < E_EDGES) ? ei[E_EDGES + e] : (e - E_EDGES);
  atomicAdd(&deg[di], 1);
}

// ---------------- K4: single-block hierarchical exclusive scan ----------------
__global__ __launch_bounds__(1024) void scan_kernel(
    const int* __restrict__ deg, int* __restrict__ row_start) {
  __shared__ int wsum[16];
  __shared__ int carry_s;
  const int tid = threadIdx.x;
  const int wv = tid >> 6, ln = tid & 63;
  if (tid == 0) { carry_s = 0; row_start[0] = 0; }
  __syncthreads();
  for (int base = 0; base < N_NODES; base += 1024) {
    int idx = base + tid;
    int v = (idx < N_NODES) ? deg[idx] : 0;
    int x = v;  // inclusive wave scan
#pragma unroll
    for (int off = 1; off < 64; off <<= 1) {
      int y = __shfl_up(x, off, 64);
      if (ln >= off) x += y;
    }
    if (ln == 63) wsum[wv] = x;
    __syncthreads();
    if (wv == 0 && ln < 16) {
      int ws = wsum[ln];
#pragma unroll
      for (int off = 1; off < 16; off <<= 1) {
        int y = __shfl_up(ws, off, 64);
        if (ln >= off) ws += y;
      }
      wsum[ln] = ws;
    }
    __syncthreads();
    int woff = (wv == 0) ? 0 : wsum[wv - 1];
    int carry = carry_s;
    int incl = carry + woff + x;
    if (idx < N_NODES) row_start[idx + 1] = incl;
    __syncthreads();
    if (tid == 1023) carry_s = incl;
    __syncthreads();
  }
}

// ---------------- K5: CSR fill (col = src sorted by dst) ----------------
__global__ __launch_bounds__(256) void fill_kernel(
    const int* __restrict__ ei, const int* __restrict__ row_start,
    int* __restrict__ cnt, int* __restrict__ col) {
  int e = blockIdx.x * 256 + threadIdx.x;
  if (e >= ETOT) return;
  int si, di;
  if (e < E_EDGES) { si = ei[e]; di = ei[E_EDGES + e]; }
  else             { si = e - E_EDGES; di = si; }
  int pos = atomicAdd(&cnt[di], 1);
  col[row_start[di] + pos] = si;
}

// ---------------- K6: fused softmax + gather aggregation ----------------
// 256 threads = 2 nodes x 128 threads (2 waves). No atomics anywhere.
__global__ __launch_bounds__(256) void agg_kernel(
    const int* __restrict__ col, const int* __restrict__ row_start,
    const float* __restrict__ h, const float* __restrict__ a_src,
    const float* __restrict__ a_dst, float* __restrict__ out) {
  __shared__ float red_m[2][2][NH];
  __shared__ float red_s[2][2][NH];
  const int tid = threadIdx.x;
  const int half = tid >> 7;           // node slot within block
  const int t = tid & 127;             // thread within node group
  const int wv = t >> 6;               // wave within node group
  const int node = blockIdx.x * 2 + half;   // grid exact: 25000*2 == N_NODES

  const int start = row_start[node];
  const int deg = row_start[node + 1] - start;
  const float4 ad = *(const float4*)(a_dst + (size_t)node * NH);

  // phase 1: online softmax (m, s) per head, strided over edges
  float m[NH], s[NH];
#pragma unroll
  for (int k = 0; k < NH; k++) { m[k] = -1e30f; s[k] = 0.f; }
  for (int j = t; j < deg; j += 128) {
    int si = col[start + j];
    float4 as = *(const float4*)(a_src + (size_t)si * NH);
    float a[NH] = {as.x + ad.x, as.y + ad.y, as.z + ad.z, as.w + ad.w};
#pragma unroll
    for (int k = 0; k < NH; k++) {
      float v = a[k] > 0.f ? a[k] : 0.2f * a[k];
      if (v > m[k]) { s[k] = s[k] * __expf(m[k] - v) + 1.f; m[k] = v; }
      else          { s[k] += __expf(v - m[k]); }
    }
  }
  // wave butterfly merge
#pragma unroll
  for (int off = 1; off < 64; off <<= 1) {
#pragma unroll
    for (int k = 0; k < NH; k++) {
      float mo = __shfl_xor(m[k], off, 64);
      float so = __shfl_xor(s[k], off, 64);
      float M = fmaxf(m[k], mo);
      s[k] = s[k] * __expf(m[k] - M) + so * __expf(mo - M);
      m[k] = M;
    }
  }
  if ((t & 63) == 0) {
#pragma unroll
    for (int k = 0; k < NH; k++) { red_m[half][wv][k] = m[k]; red_s[half][wv][k] = s[k]; }
  }
  __syncthreads();

  const int c = t;            // output component 0..127
  const int head = t >> 5;    // 0..3
  float m0 = red_m[half][0][head], s0 = red_s[half][0][head];
  float m1 = red_m[half][1][head], s1 = red_s[half][1][head];
  float M = fmaxf(m0, m1);
  float S = s0 * __expf(m0 - M) + s1 * __expf(m1 - M);
  float inv_s = 1.0f / S;
  const float adh = (head == 0) ? ad.x : (head == 1) ? ad.y : (head == 2) ? ad.z : ad.w;

  // phase 2: gather-accumulate, unrolled x4 for MLP
  float acc = 0.f;
  int j = 0;
  for (; j + 4 <= deg; j += 4) {
    int si0 = col[start + j];
    int si1 = col[start + j + 1];
    int si2 = col[start + j + 2];
    int si3 = col[start + j + 3];
    float a0 = a_src[(size_t)si0 * NH + head] + adh;
    float a1 = a_src[(size_t)si1 * NH + head] + adh;
    float a2 = a_src[(size_t)si2 * NH + head] + adh;
    float a3 = a_src[(size_t)si3 * NH + head] + adh;
    float h0 = h[(size_t)si0 * DOUT + c];
    float h1 = h[(size_t)si1 * DOUT + c];
    float h2 = h[(size_t)si2 * DOUT + c];
    float h3 = h[(size_t)si3 * DOUT + c];
    a0 = a0 > 0.f ? a0 : 0.2f * a0;
    a1 = a1 > 0.f ? a1 : 0.2f * a1;
    a2 = a2 > 0.f ? a2 : 0.2f * a2;
    a3 = a3 > 0.f ? a3 : 0.2f * a3;
    acc += h0 * (__expf(a0 - M) * inv_s + 1.f);
    acc += h1 * (__expf(a1 - M) * inv_s + 1.f);
    acc += h2 * (__expf(a2 - M) * inv_s + 1.f);
    acc += h3 * (__expf(a3 - M) * inv_s + 1.f);
  }
  for (; j < deg; j++) {
    int si = col[start + j];
    float a = a_src[(size_t)si * NH + head] + adh;
    a = a > 0.f ? a : 0.2f * a;
    acc += h[(size_t)si * DOUT + c] * (__expf(a - M) * inv_s + 1.f);
  }
  out[(size_t)node * DOUT + c] = acc;
}

extern "C" void kernel_launch(void* const* d_in, const int* in_sizes, int n_in,
                              void* d_out, int out_size, void* d_ws, size_t ws_size,
                              hipStream_t stream) {
  const float* x       = (const float*)d_in[0];
  const int*   ei      = (const int*)d_in[1];
  const float* W       = (const float*)d_in[2];
  const float* att_src = (const float*)d_in[3];
  const float* att_dst = (const float*)d_in[4];
  float* out = (float*)d_out;

  // workspace layout: h | a_src | a_dst | deg | cnt | row_start | col
  float* ws    = (float*)d_ws;
  float* h     = ws;
  float* a_src = h + (size_t)N_NODES * DOUT;
  float* a_dst = a_src + (size_t)N_NODES * NH;
  int* deg       = (int*)(a_dst + (size_t)N_NODES * NH);
  int* cnt       = deg + N_NODES;
  int* row_start = cnt + N_NODES;          // N_NODES + 1
  int* col       = row_start + N_NODES + 1;  // ETOT

  // zero deg + cnt in one shot (adjacent)
  hipMemsetAsync(deg, 0, (size_t)2 * N_NODES * sizeof(int), stream);

  gemm_kernel<<<(N_NODES + 63) / 64, 512, 0, stream>>>(x, W, h);
  att_logits_kernel<<<(N_NODES * NH + 255) / 256, 256, 0, stream>>>(
      h, att_src, att_dst, a_src, a_dst);
  deg_kernel<<<(ETOT + 255) / 256, 256, 0, stream>>>(ei, deg);
  scan_kernel<<<1, 1024, 0, stream>>>(deg, row_start);
  fill_kernel<<<(ETOT + 255) / 256, 256, 0, stream>>>(ei, row_start, cnt, col);
  agg_kernel<<<N_NODES / 2, 256, 0, stream>>>(col, row_start, h, a_src, a_dst, out);
}

// Round 3
// 369.804 us; speedup vs baseline: 3.7193x; 1.1803x over previous
//
#include <hip/hip_runtime.h>

#define N_NODES 50000
#define E_EDGES 1600000
#define ETOT    (E_EDGES + N_NODES)
#define DIN  128
#define DOUT 128
#define NH   4
#define HD   32

// ---------------- K1: h = x @ W^T  (fp32, W in LDS swizzled) ----------------
// 512 threads, 64 nodes/block. x rows read directly from global (wave-uniform
// broadcast loads, L1-resident 32KB tile). W staged once, XOR-swizzled so the
// per-column float4 reads are bank-conflict-free. LDS 64KB -> 2 blocks/CU.
__global__ __launch_bounds__(512, 4) void gemm_kernel(
    const float* __restrict__ x, const float* __restrict__ W,
    float* __restrict__ h) {
  __shared__ float Ws[DIN * DOUT];  // 64 KB, float4-chunk swizzled
  const int tid = threadIdx.x;
  for (int i = tid; i < DIN * DOUT; i += 512) {
    int o = i >> 7, k = i & 127;
    int kk = k >> 2, r = k & 3;
    Ws[(o << 7) + (((kk ^ (o & 7)) << 2) | r)] = W[i];
  }
  __syncthreads();

  const int g = tid >> 6;       // wave id 0..7 -> node sub-tile
  const int l = tid & 63;       // columns l and l+64
  const int n0 = blockIdx.x * 64 + g * 8;
  const int c0 = l, c1 = l + 64;
  const int sw = c0 & 7;        // (c1 & 7) == (c0 & 7)
  const float* w0base = Ws + (c0 << 7);
  const float* w1base = Ws + (c1 << 7);

  const float* xp[8];
#pragma unroll
  for (int i = 0; i < 8; i++) {
    int n = n0 + i;
    if (n >= N_NODES) n = N_NODES - 1;   // clamp (stores guarded below)
    xp[i] = x + (size_t)n * DIN;
  }

  float acc0[8], acc1[8];
#pragma unroll
  for (int i = 0; i < 8; i++) { acc0[i] = 0.f; acc1[i] = 0.f; }

  for (int kk = 0; kk < 32; kk++) {
    const int ko = (kk ^ sw) << 2;
    const float4 wa = *(const float4*)(w0base + ko);
    const float4 wb = *(const float4*)(w1base + ko);
    const int k = kk << 2;
#pragma unroll
    for (int i = 0; i < 8; i++) {
      const float4 xv = *(const float4*)(xp[i] + k);
      acc0[i] = fmaf(xv.x, wa.x, acc0[i]);
      acc0[i] = fmaf(xv.y, wa.y, acc0[i]);
      acc0[i] = fmaf(xv.z, wa.z, acc0[i]);
      acc0[i] = fmaf(xv.w, wa.w, acc0[i]);
      acc1[i] = fmaf(xv.x, wb.x, acc1[i]);
      acc1[i] = fmaf(xv.y, wb.y, acc1[i]);
      acc1[i] = fmaf(xv.z, wb.z, acc1[i]);
      acc1[i] = fmaf(xv.w, wb.w, acc1[i]);
    }
  }
#pragma unroll
  for (int i = 0; i < 8; i++) {
    int n = n0 + i;
    if (n < N_NODES) {
      h[(size_t)n * DOUT + c0] = acc0[i];
      h[(size_t)n * DOUT + c1] = acc1[i];
    }
  }
}

// ---------------- K2: per-node attention logits ----------------
__global__ __launch_bounds__(256) void att_logits_kernel(
    const float* __restrict__ h, const float* __restrict__ att_src,
    const float* __restrict__ att_dst, float* __restrict__ a_src,
    float* __restrict__ a_dst) {
  int t = blockIdx.x * 256 + threadIdx.x;
  if (t >= N_NODES * NH) return;
  int n = t >> 2, hd = t & 3;
  const float* hp = h + (size_t)n * DOUT + hd * HD;
  const float* as = att_src + hd * HD;
  const float* ad = att_dst + hd * HD;
  float s1 = 0.f, s2 = 0.f;
#pragma unroll
  for (int j = 0; j < HD; j += 4) {
    float4 hv = *(const float4*)(hp + j);
    float4 av = *(const float4*)(as + j);
    float4 dv = *(const float4*)(ad + j);
    s1 += hv.x * av.x + hv.y * av.y + hv.z * av.z + hv.w * av.w;
    s2 += hv.x * dv.x + hv.y * dv.y + hv.z * dv.z + hv.w * dv.w;
  }
  a_src[t] = s1;
  a_dst[t] = s2;
}

// ---------------- K3: degree count ----------------
__global__ __launch_bounds__(256) void deg_kernel(
    const int* __restrict__ ei, int* __restrict__ deg) {
  int e = blockIdx.x * 256 + threadIdx.x;
  if (e >= ETOT) return;
  int di = (e < E_EDGES) ? ei[E_EDGES + e] : (e - E_EDGES);
  atomicAdd(&deg[di], 1);
}

// ---------------- K4a/b/c: parallel exclusive scan (3 kernels) ----------------
#define SCAN_NB ((N_NODES + 1023) / 1024)   // 49
__global__ __launch_bounds__(1024) void scan1_kernel(
    const int* __restrict__ deg, int* __restrict__ incl, int* __restrict__ part) {
  __shared__ int wsum[16];
  const int tid = threadIdx.x;
  const int wv = tid >> 6, ln = tid & 63;
  const int idx = blockIdx.x * 1024 + tid;
  int v = (idx < N_NODES) ? deg[idx] : 0;
  int xx = v;
#pragma unroll
  for (int off = 1; off < 64; off <<= 1) {
    int y = __shfl_up(xx, off, 64);
    if (ln >= off) xx += y;
  }
  if (ln == 63) wsum[wv] = xx;
  __syncthreads();
  if (tid < 16) {
    int ws = wsum[tid];
#pragma unroll
    for (int off = 1; off < 16; off <<= 1) {
      int y = __shfl_up(ws, off, 64);
      if (tid >= off) ws += y;
    }
    wsum[tid] = ws;
  }
  __syncthreads();
  int woff = (wv == 0) ? 0 : wsum[wv - 1];
  if (idx < N_NODES) incl[idx] = xx + woff;
  if (tid == 1023) part[blockIdx.x] = xx + woff;
}

__global__ __launch_bounds__(64) void scan2_kernel(int* __restrict__ part) {
  const int tid = threadIdx.x;
  int v = (tid < SCAN_NB) ? part[tid] : 0;
  int xx = v;
#pragma unroll
  for (int off = 1; off < 64; off <<= 1) {
    int y = __shfl_up(xx, off, 64);
    if (tid >= off) xx += y;
  }
  if (tid < SCAN_NB) part[tid] = xx - v;   // exclusive
}

__global__ __launch_bounds__(1024) void scan3_kernel(
    const int* __restrict__ incl, const int* __restrict__ part,
    int* __restrict__ row_start) {
  const int idx = blockIdx.x * 1024 + threadIdx.x;
  if (idx < N_NODES) row_start[idx + 1] = incl[idx] + part[blockIdx.x];
  if (idx == 0) row_start[0] = 0;
}

// ---------------- K5: CSR fill (deg used as countdown counter) ----------------
__global__ __launch_bounds__(256) void fill_kernel(
    const int* __restrict__ ei, const int* __restrict__ row_start,
    int* __restrict__ deg, int* __restrict__ col) {
  int e = blockIdx.x * 256 + threadIdx.x;
  if (e >= ETOT) return;
  int si, di;
  if (e < E_EDGES) { si = ei[e]; di = ei[E_EDGES + e]; }
  else             { si = e - E_EDGES; di = si; }
  int pos = atomicSub(&deg[di], 1) - 1;
  col[row_start[di] + pos] = si;
}

// ---------------- K6: fused softmax + gather aggregation ----------------
// 256 threads = 8 nodes x 32 threads. Each thread owns 4 output components
// (float4). Per-edge softmax weights computed ONCE into LDS (32-edge chunks),
// consumed as broadcast reads. Slot group = half-wave -> no __syncthreads.
#define NPB 8
#define CH  32
#define MERGE(mv, sv)                                    \
  {                                                      \
    float mo_ = __shfl_xor(mv, off);                     \
    float so_ = __shfl_xor(sv, off);                     \
    float MM_ = fmaxf(mv, mo_);                          \
    sv = sv * __expf(mv - MM_) + so_ * __expf(mo_ - MM_);\
    mv = MM_;                                            \
  }

__global__ __launch_bounds__(256, 6) void agg_kernel(
    const int* __restrict__ col, const int* __restrict__ row_start,
    const float* __restrict__ h, const float* __restrict__ a_src,
    const float* __restrict__ a_dst, float* __restrict__ out) {
  __shared__ float w_lds[NPB][CH][NH];   // 4 KB
  __shared__ int   si_lds[NPB][CH];      // 1 KB
  const int tid  = threadIdx.x;
  const int slot = tid >> 5;
  const int t    = tid & 31;
  const int node = blockIdx.x * NPB + slot;   // grid exact: 6250*8 == N_NODES
  const int start = row_start[node];
  const int deg   = row_start[node + 1] - start;
  const float4 ad = *(const float4*)(a_dst + (size_t)node * NH);

  // phase 1: online (m,s) per head over this node's edges, 32 threads
  float m0 = -1e30f, m1 = -1e30f, m2 = -1e30f, m3 = -1e30f;
  float s0 = 0.f, s1 = 0.f, s2 = 0.f, s3 = 0.f;
  for (int j = t; j < deg; j += 32) {
    int si = col[start + j];
    float4 as = *(const float4*)(a_src + (size_t)si * NH);
    float v0 = as.x + ad.x; v0 = v0 > 0.f ? v0 : 0.2f * v0;
    float v1 = as.y + ad.y; v1 = v1 > 0.f ? v1 : 0.2f * v1;
    float v2 = as.z + ad.z; v2 = v2 > 0.f ? v2 : 0.2f * v2;
    float v3 = as.w + ad.w; v3 = v3 > 0.f ? v3 : 0.2f * v3;
    float n0 = fmaxf(m0, v0); s0 = s0 * __expf(m0 - n0) + __expf(v0 - n0); m0 = n0;
    float n1 = fmaxf(m1, v1); s1 = s1 * __expf(m1 - n1) + __expf(v1 - n1); m1 = n1;
    float n2 = fmaxf(m2, v2); s2 = s2 * __expf(m2 - n2) + __expf(v2 - n2); m2 = n2;
    float n3 = fmaxf(m3, v3); s3 = s3 * __expf(m3 - n3) + __expf(v3 - n3); m3 = n3;
  }
#pragma unroll
  for (int off = 1; off < 32; off <<= 1) {
    MERGE(m0, s0) MERGE(m1, s1) MERGE(m2, s2) MERGE(m3, s3)
  }
  const float i0 = 1.f / s0, i1 = 1.f / s1, i2 = 1.f / s2, i3 = 1.f / s3;

  const int head = t >> 3;          // c4>>5
  const int c4 = t << 2;
  const float Mh = head == 0 ? m0 : head == 1 ? m1 : head == 2 ? m2 : m3;
  (void)Mh;
  const float* hc = h + c4;
  float4 acc = make_float4(0.f, 0.f, 0.f, 0.f);

  for (int base = 0; base < deg; base += CH) {
    int nch = deg - base;
    if (nch > CH) nch = CH;
    if (t < nch) {
      int si = col[start + base + t];
      si_lds[slot][t] = si;
      float4 as = *(const float4*)(a_src + (size_t)si * NH);
      float v0 = as.x + ad.x; v0 = v0 > 0.f ? v0 : 0.2f * v0;
      float v1 = as.y + ad.y; v1 = v1 > 0.f ? v1 : 0.2f * v1;
      float v2 = as.z + ad.z; v2 = v2 > 0.f ? v2 : 0.2f * v2;
      float v3 = as.w + ad.w; v3 = v3 > 0.f ? v3 : 0.2f * v3;
      w_lds[slot][t][0] = __expf(v0 - m0) * i0 + 1.f;
      w_lds[slot][t][1] = __expf(v1 - m1) * i1 + 1.f;
      w_lds[slot][t][2] = __expf(v2 - m2) * i2 + 1.f;
      w_lds[slot][t][3] = __expf(v3 - m3) * i3 + 1.f;
    }
    // same-wave producer/consumer: DS pipe is in-order per wave; fence stops
    // compiler reordering across the stage<->consume boundary.
    __builtin_amdgcn_fence(__ATOMIC_ACQ_REL, "wavefront");
    for (int j = 0; j < nch; j++) {
      int si = si_lds[slot][j];
      float w = w_lds[slot][j][head];
      const float4 hv = *(const float4*)(hc + ((size_t)si << 7));
      acc.x = fmaf(hv.x, w, acc.x);
      acc.y = fmaf(hv.y, w, acc.y);
      acc.z = fmaf(hv.z, w, acc.z);
      acc.w = fmaf(hv.w, w, acc.w);
    }
    __builtin_amdgcn_fence(__ATOMIC_ACQ_REL, "wavefront");
  }
  *(float4*)(out + (size_t)node * DOUT + c4) = acc;
}

extern "C" void kernel_launch(void* const* d_in, const int* in_sizes, int n_in,
                              void* d_out, int out_size, void* d_ws, size_t ws_size,
                              hipStream_t stream) {
  const float* x       = (const float*)d_in[0];
  const int*   ei      = (const int*)d_in[1];
  const float* W       = (const float*)d_in[2];
  const float* att_src = (const float*)d_in[3];
  const float* att_dst = (const float*)d_in[4];
  float* out = (float*)d_out;

  // workspace: h | a_src | a_dst | deg | row_start | col | incl | part
  float* ws    = (float*)d_ws;
  float* h     = ws;
  float* a_src = h + (size_t)N_NODES * DOUT;
  float* a_dst = a_src + (size_t)N_NODES * NH;
  int* deg       = (int*)(a_dst + (size_t)N_NODES * NH);
  int* row_start = deg + N_NODES;            // N_NODES + 1
  int* col       = row_start + N_NODES + 1;  // ETOT
  int* incl      = col + ETOT;               // N_NODES
  int* part      = incl + N_NODES;           // SCAN_NB

  hipMemsetAsync(deg, 0, (size_t)N_NODES * sizeof(int), stream);

  gemm_kernel<<<(N_NODES + 63) / 64, 512, 0, stream>>>(x, W, h);
  att_logits_kernel<<<(N_NODES * NH + 255) / 256, 256, 0, stream>>>(
      h, att_src, att_dst, a_src, a_dst);
  deg_kernel<<<(ETOT + 255) / 256, 256, 0, stream>>>(ei, deg);
  scan1_kernel<<<SCAN_NB, 1024, 0, stream>>>(deg, incl, part);
  scan2_kernel<<<1, 64, 0, stream>>>(part);
  scan3_kernel<<<SCAN_NB, 1024, 0, stream>>>(incl, part, row_start);
  fill_kernel<<<(ETOT + 255) / 256, 256, 0, stream>>>(ei, row_start, deg, col);
  agg_kernel<<<N_NODES / NPB, 256, 0, stream>>>(col, row_start, h, a_src, a_dst, out);
}

// Round 4
// 316.613 us; speedup vs baseline: 4.3441x; 1.1680x over previous
//
#include <hip/hip_runtime.h>

#define N_NODES 50000
#define E_EDGES 1600000
#define ETOT    (E_EDGES + N_NODES)
#define DIN  128
#define DOUT 128
#define NH   4
#define HD   32

typedef unsigned short ushort_t;
typedef unsigned int uint_t;

__device__ __forceinline__ ushort_t f2bf(float f) {
  uint_t u = __float_as_uint(f);
  u += 0x7fffu + ((u >> 16) & 1u);   // RNE
  return (ushort_t)(u >> 16);
}
__device__ __forceinline__ float bf_lo(uint_t u) {
  return __uint_as_float(u << 16);
}
__device__ __forceinline__ float bf_hi(uint_t u) {
  return __uint_as_float(u & 0xffff0000u);
}

// ---------------- K1: h = x @ W^T  (fp32 math, bf16 output) ----------------
// 512 threads, 64 nodes/block. x rows read as wave-uniform global loads (L1);
// W staged in LDS, XOR-swizzled float4 chunks -> conflict-free b128 reads.
__global__ __launch_bounds__(512, 4) void gemm_kernel(
    const float* __restrict__ x, const float* __restrict__ W,
    ushort_t* __restrict__ hb) {
  __shared__ float Ws[DIN * DOUT];  // 64 KB
  const int tid = threadIdx.x;
  for (int i = tid; i < DIN * DOUT; i += 512) {
    int o = i >> 7, k = i & 127;
    int kk = k >> 2, r = k & 3;
    Ws[(o << 7) + (((kk ^ (o & 7)) << 2) | r)] = W[i];
  }
  __syncthreads();

  const int g = tid >> 6;
  const int l = tid & 63;
  const int n0 = blockIdx.x * 64 + g * 8;
  const int c0 = l, c1 = l + 64;
  const int sw = c0 & 7;
  const float* w0base = Ws + (c0 << 7);
  const float* w1base = Ws + (c1 << 7);

  const float* xp[8];
#pragma unroll
  for (int i = 0; i < 8; i++) {
    int n = n0 + i;
    if (n >= N_NODES) n = N_NODES - 1;
    xp[i] = x + (size_t)n * DIN;
  }

  float acc0[8], acc1[8];
#pragma unroll
  for (int i = 0; i < 8; i++) { acc0[i] = 0.f; acc1[i] = 0.f; }

  for (int kk = 0; kk < 32; kk++) {
    const int ko = (kk ^ sw) << 2;
    const float4 wa = *(const float4*)(w0base + ko);
    const float4 wb = *(const float4*)(w1base + ko);
    const int k = kk << 2;
#pragma unroll
    for (int i = 0; i < 8; i++) {
      const float4 xv = *(const float4*)(xp[i] + k);
      acc0[i] = fmaf(xv.x, wa.x, acc0[i]);
      acc0[i] = fmaf(xv.y, wa.y, acc0[i]);
      acc0[i] = fmaf(xv.z, wa.z, acc0[i]);
      acc0[i] = fmaf(xv.w, wa.w, acc0[i]);
      acc1[i] = fmaf(xv.x, wb.x, acc1[i]);
      acc1[i] = fmaf(xv.y, wb.y, acc1[i]);
      acc1[i] = fmaf(xv.z, wb.z, acc1[i]);
      acc1[i] = fmaf(xv.w, wb.w, acc1[i]);
    }
  }
#pragma unroll
  for (int i = 0; i < 8; i++) {
    int n = n0 + i;
    if (n < N_NODES) {
      hb[((size_t)n << 7) + c0] = f2bf(acc0[i]);
      hb[((size_t)n << 7) + c1] = f2bf(acc1[i]);
    }
  }
}

// ---------------- K2: per-node attention logits (reads bf16 h) ----------------
__global__ __launch_bounds__(256) void att_logits_kernel(
    const ushort_t* __restrict__ hb, const float* __restrict__ att_src,
    const float* __restrict__ att_dst, float* __restrict__ a_src,
    float* __restrict__ a_dst) {
  int t = blockIdx.x * 256 + threadIdx.x;
  if (t >= N_NODES * NH) return;
  int n = t >> 2, hd = t & 3;
  const uint4* hp = (const uint4*)(hb + ((size_t)n << 7) + (hd << 5));
  const float* as = att_src + (hd << 5);
  const float* ad = att_dst + (hd << 5);
  float s1 = 0.f, s2 = 0.f;
#pragma unroll
  for (int q = 0; q < 4; q++) {
    uint4 hv = hp[q];
    float c0 = bf_lo(hv.x), c1 = bf_hi(hv.x);
    float c2 = bf_lo(hv.y), c3 = bf_hi(hv.y);
    float c4 = bf_lo(hv.z), c5 = bf_hi(hv.z);
    float c6 = bf_lo(hv.w), c7 = bf_hi(hv.w);
    float4 a0 = *(const float4*)(as + q * 8);
    float4 a1 = *(const float4*)(as + q * 8 + 4);
    float4 d0 = *(const float4*)(ad + q * 8);
    float4 d1 = *(const float4*)(ad + q * 8 + 4);
    s1 += c0*a0.x + c1*a0.y + c2*a0.z + c3*a0.w + c4*a1.x + c5*a1.y + c6*a1.z + c7*a1.w;
    s2 += c0*d0.x + c1*d0.y + c2*d0.z + c3*d0.w + c4*d1.x + c5*d1.y + c6*d1.z + c7*d1.w;
  }
  a_src[t] = s1;
  a_dst[t] = s2;
}

// ---------------- K3: degree count ----------------
__global__ __launch_bounds__(256) void deg_kernel(
    const int* __restrict__ ei, int* __restrict__ deg) {
  int e = blockIdx.x * 256 + threadIdx.x;
  if (e >= ETOT) return;
  int di = (e < E_EDGES) ? ei[E_EDGES + e] : (e - E_EDGES);
  atomicAdd(&deg[di], 1);
}

// ---------------- K4a/b/c: parallel exclusive scan ----------------
#define SCAN_NB ((N_NODES + 1023) / 1024)   // 49
__global__ __launch_bounds__(1024) void scan1_kernel(
    const int* __restrict__ deg, int* __restrict__ incl, int* __restrict__ part) {
  __shared__ int wsum[16];
  const int tid = threadIdx.x;
  const int wv = tid >> 6, ln = tid & 63;
  const int idx = blockIdx.x * 1024 + tid;
  int v = (idx < N_NODES) ? deg[idx] : 0;
  int xx = v;
#pragma unroll
  for (int off = 1; off < 64; off <<= 1) {
    int y = __shfl_up(xx, off, 64);
    if (ln >= off) xx += y;
  }
  if (ln == 63) wsum[wv] = xx;
  __syncthreads();
  if (tid < 16) {
    int ws = wsum[tid];
#pragma unroll
    for (int off = 1; off < 16; off <<= 1) {
      int y = __shfl_up(ws, off, 64);
      if (tid >= off) ws += y;
    }
    wsum[tid] = ws;
  }
  __syncthreads();
  int woff = (wv == 0) ? 0 : wsum[wv - 1];
  if (idx < N_NODES) incl[idx] = xx + woff;
  if (tid == 1023) part[blockIdx.x] = xx + woff;
}

__global__ __launch_bounds__(64) void scan2_kernel(int* __restrict__ part) {
  const int tid = threadIdx.x;
  int v = (tid < SCAN_NB) ? part[tid] : 0;
  int xx = v;
#pragma unroll
  for (int off = 1; off < 64; off <<= 1) {
    int y = __shfl_up(xx, off, 64);
    if (tid >= off) xx += y;
  }
  if (tid < SCAN_NB) part[tid] = xx - v;
}

__global__ __launch_bounds__(1024) void scan3_kernel(
    const int* __restrict__ incl, const int* __restrict__ part,
    int* __restrict__ row_start) {
  const int idx = blockIdx.x * 1024 + threadIdx.x;
  if (idx < N_NODES) row_start[idx + 1] = incl[idx] + part[blockIdx.x];
  if (idx == 0) row_start[0] = 0;
}

// ---------------- K5: CSR fill (deg as countdown) ----------------
__global__ __launch_bounds__(256) void fill_kernel(
    const int* __restrict__ ei, const int* __restrict__ row_start,
    int* __restrict__ deg, int* __restrict__ col) {
  int e = blockIdx.x * 256 + threadIdx.x;
  if (e >= ETOT) return;
  int si, di;
  if (e < E_EDGES) { si = ei[e]; di = ei[E_EDGES + e]; }
  else             { si = e - E_EDGES; di = si; }
  int pos = atomicSub(&deg[di], 1) - 1;
  col[row_start[di] + pos] = si;
}

// ---------------- K6: fused softmax + gather aggregation (bf16 h) ----------
// 256 threads = 16 nodes x 16 threads. Each thread: 8 comps (one 16B uint4
// of bf16 per edge). Per-edge softmax weight computed once into LDS.
#define NPB 16
#define CH  16
#define MERGE(mv, sv)                                    \
  {                                                      \
    float mo_ = __shfl_xor(mv, off);                     \
    float so_ = __shfl_xor(sv, off);                     \
    float MM_ = fmaxf(mv, mo_);                          \
    sv = sv * __expf(mv - MM_) + so_ * __expf(mo_ - MM_);\
    mv = MM_;                                            \
  }

__global__ __launch_bounds__(256, 8) void agg_kernel(
    const int* __restrict__ col, const int* __restrict__ row_start,
    const ushort_t* __restrict__ hb, const float* __restrict__ a_src,
    const float* __restrict__ a_dst, float* __restrict__ out) {
  __shared__ float w_lds[NPB][CH][NH];   // 4 KB
  __shared__ int   si_lds[NPB][CH];      // 1 KB
  const int tid  = threadIdx.x;
  const int slot = tid >> 4;
  const int t    = tid & 15;
  const int node = blockIdx.x * NPB + slot;   // 3125*16 == N_NODES exactly
  const int start = row_start[node];
  const int deg   = row_start[node + 1] - start;
  const float4 ad = *(const float4*)(a_dst + (size_t)node * NH);

  // phase 1: online (m,s) per head, 16 threads strided
  float m0 = -1e30f, m1 = -1e30f, m2 = -1e30f, m3 = -1e30f;
  float s0 = 0.f, s1 = 0.f, s2 = 0.f, s3 = 0.f;
  for (int j = t; j < deg; j += 16) {
    int si = col[start + j];
    float4 as = *(const float4*)(a_src + (size_t)si * NH);
    float v0 = as.x + ad.x; v0 = v0 > 0.f ? v0 : 0.2f * v0;
    float v1 = as.y + ad.y; v1 = v1 > 0.f ? v1 : 0.2f * v1;
    float v2 = as.z + ad.z; v2 = v2 > 0.f ? v2 : 0.2f * v2;
    float v3 = as.w + ad.w; v3 = v3 > 0.f ? v3 : 0.2f * v3;
    float n0 = fmaxf(m0, v0); s0 = s0 * __expf(m0 - n0) + __expf(v0 - n0); m0 = n0;
    float n1 = fmaxf(m1, v1); s1 = s1 * __expf(m1 - n1) + __expf(v1 - n1); m1 = n1;
    float n2 = fmaxf(m2, v2); s2 = s2 * __expf(m2 - n2) + __expf(v2 - n2); m2 = n2;
    float n3 = fmaxf(m3, v3); s3 = s3 * __expf(m3 - n3) + __expf(v3 - n3); m3 = n3;
  }
#pragma unroll
  for (int off = 1; off < 16; off <<= 1) {   // stays within 16-lane group
    MERGE(m0, s0) MERGE(m1, s1) MERGE(m2, s2) MERGE(m3, s3)
  }
  const float i0 = 1.f / s0, i1 = 1.f / s1, i2 = 1.f / s2, i3 = 1.f / s3;

  const int head = t >> 2;          // 8 comps all in one head
  const int c8 = t << 3;
  const ushort_t* hc = hb + c8;
  float a0 = 0.f, a1 = 0.f, a2 = 0.f, a3 = 0.f;
  float a4 = 0.f, a5 = 0.f, a6 = 0.f, a7 = 0.f;

  for (int base_e = 0; base_e < deg; base_e += CH) {
    int nch = deg - base_e;
    if (nch > CH) nch = CH;
    if (t < nch) {
      int si = col[start + base_e + t];
      si_lds[slot][t] = si;
      float4 as = *(const float4*)(a_src + (size_t)si * NH);
      float v0 = as.x + ad.x; v0 = v0 > 0.f ? v0 : 0.2f * v0;
      float v1 = as.y + ad.y; v1 = v1 > 0.f ? v1 : 0.2f * v1;
      float v2 = as.z + ad.z; v2 = v2 > 0.f ? v2 : 0.2f * v2;
      float v3 = as.w + ad.w; v3 = v3 > 0.f ? v3 : 0.2f * v3;
      w_lds[slot][t][0] = __expf(v0 - m0) * i0 + 1.f;
      w_lds[slot][t][1] = __expf(v1 - m1) * i1 + 1.f;
      w_lds[slot][t][2] = __expf(v2 - m2) * i2 + 1.f;
      w_lds[slot][t][3] = __expf(v3 - m3) * i3 + 1.f;
    }
    __builtin_amdgcn_fence(__ATOMIC_ACQ_REL, "wavefront");
#pragma unroll 2
    for (int j = 0; j < nch; j++) {
      int si = si_lds[slot][j];
      float w = w_lds[slot][j][head];
      const uint4 hv = *(const uint4*)(hc + ((size_t)si << 7));
      a0 = fmaf(bf_lo(hv.x), w, a0);
      a1 = fmaf(bf_hi(hv.x), w, a1);
      a2 = fmaf(bf_lo(hv.y), w, a2);
      a3 = fmaf(bf_hi(hv.y), w, a3);
      a4 = fmaf(bf_lo(hv.z), w, a4);
      a5 = fmaf(bf_hi(hv.z), w, a5);
      a6 = fmaf(bf_lo(hv.w), w, a6);
      a7 = fmaf(bf_hi(hv.w), w, a7);
    }
    __builtin_amdgcn_fence(__ATOMIC_ACQ_REL, "wavefront");
  }
  float* op = out + ((size_t)node << 7) + c8;
  *(float4*)(op)     = make_float4(a0, a1, a2, a3);
  *(float4*)(op + 4) = make_float4(a4, a5, a6, a7);
}

extern "C" void kernel_launch(void* const* d_in, const int* in_sizes, int n_in,
                              void* d_out, int out_size, void* d_ws, size_t ws_size,
                              hipStream_t stream) {
  const float* x       = (const float*)d_in[0];
  const int*   ei      = (const int*)d_in[1];
  const float* W       = (const float*)d_in[2];
  const float* att_src = (const float*)d_in[3];
  const float* att_dst = (const float*)d_in[4];
  float* out = (float*)d_out;

  // workspace: hb(bf16) | a_src | a_dst | deg | row_start | col | incl | part
  ushort_t* hb = (ushort_t*)d_ws;
  float* a_src = (float*)(hb + (size_t)N_NODES * DOUT);
  float* a_dst = a_src + (size_t)N_NODES * NH;
  int* deg       = (int*)(a_dst + (size_t)N_NODES * NH);
  int* row_start = deg + N_NODES;            // N_NODES + 1
  int* col       = row_start + N_NODES + 1;  // ETOT
  int* incl      = col + ETOT;               // N_NODES
  int* part      = incl + N_NODES;           // SCAN_NB

  hipMemsetAsync(deg, 0, (size_t)N_NODES * sizeof(int), stream);

  gemm_kernel<<<(N_NODES + 63) / 64, 512, 0, stream>>>(x, W, hb);
  att_logits_kernel<<<(N_NODES * NH + 255) / 256, 256, 0, stream>>>(
      hb, att_src, att_dst, a_src, a_dst);
  deg_kernel<<<(ETOT + 255) / 256, 256, 0, stream>>>(ei, deg);
  scan1_kernel<<<SCAN_NB, 1024, 0, stream>>>(deg, incl, part);
  scan2_kernel<<<1, 64, 0, stream>>>(part);
  scan3_kernel<<<SCAN_NB, 1024, 0, stream>>>(incl, part, row_start);
  fill_kernel<<<(ETOT + 255) / 256, 256, 0, stream>>>(ei, row_start, deg, col);
  agg_kernel<<<N_NODES / NPB, 256, 0, stream>>>(col, row_start, hb, a_src, a_dst, out);
}

// Round 6
// 301.967 us; speedup vs baseline: 4.5548x; 1.0485x over previous
//
#include <hip/hip_runtime.h>

#define N_NODES 50000
#define E_EDGES 1600000
#define ETOT    (E_EDGES + N_NODES)
#define DIN  128
#define DOUT 128
#define NH   4
#define HD   32

typedef unsigned short ushort_t;
typedef unsigned int uint_t;

__device__ __forceinline__ ushort_t f2bf(float f) {
  uint_t u = __float_as_uint(f);
  u += 0x7fffu + ((u >> 16) & 1u);   // RNE
  return (ushort_t)(u >> 16);
}
__device__ __forceinline__ float bf_lo(uint_t u) {
  return __uint_as_float(u << 16);
}
__device__ __forceinline__ float bf_hi(uint_t u) {
  return __uint_as_float(u & 0xffff0000u);
}

// ---------------- K1: h = x @ W^T  (fp32 math, bf16 output) ----------------
__global__ __launch_bounds__(512, 4) void gemm_kernel(
    const float* __restrict__ x, const float* __restrict__ W,
    ushort_t* __restrict__ hb) {
  __shared__ float Ws[DIN * DOUT];  // 64 KB
  const int tid = threadIdx.x;
  for (int i = tid; i < DIN * DOUT; i += 512) {
    int o = i >> 7, k = i & 127;
    int kk = k >> 2, r = k & 3;
    Ws[(o << 7) + (((kk ^ (o & 7)) << 2) | r)] = W[i];
  }
  __syncthreads();

  const int g = tid >> 6;
  const int l = tid & 63;
  const int n0 = blockIdx.x * 64 + g * 8;
  const int c0 = l, c1 = l + 64;
  const int sw = c0 & 7;
  const float* w0base = Ws + (c0 << 7);
  const float* w1base = Ws + (c1 << 7);

  const float* xp[8];
#pragma unroll
  for (int i = 0; i < 8; i++) {
    int n = n0 + i;
    if (n >= N_NODES) n = N_NODES - 1;
    xp[i] = x + (size_t)n * DIN;
  }

  float acc0[8], acc1[8];
#pragma unroll
  for (int i = 0; i < 8; i++) { acc0[i] = 0.f; acc1[i] = 0.f; }

  for (int kk = 0; kk < 32; kk++) {
    const int ko = (kk ^ sw) << 2;
    const float4 wa = *(const float4*)(w0base + ko);
    const float4 wb = *(const float4*)(w1base + ko);
    const int k = kk << 2;
#pragma unroll
    for (int i = 0; i < 8; i++) {
      const float4 xv = *(const float4*)(xp[i] + k);
      acc0[i] = fmaf(xv.x, wa.x, acc0[i]);
      acc0[i] = fmaf(xv.y, wa.y, acc0[i]);
      acc0[i] = fmaf(xv.z, wa.z, acc0[i]);
      acc0[i] = fmaf(xv.w, wa.w, acc0[i]);
      acc1[i] = fmaf(xv.x, wb.x, acc1[i]);
      acc1[i] = fmaf(xv.y, wb.y, acc1[i]);
      acc1[i] = fmaf(xv.z, wb.z, acc1[i]);
      acc1[i] = fmaf(xv.w, wb.w, acc1[i]);
    }
  }
#pragma unroll
  for (int i = 0; i < 8; i++) {
    int n = n0 + i;
    if (n < N_NODES) {
      hb[((size_t)n << 7) + c0] = f2bf(acc0[i]);
      hb[((size_t)n << 7) + c1] = f2bf(acc1[i]);
    }
  }
}

// ---------------- K2: per-node attention logits (reads bf16 h) ------------
__global__ __launch_bounds__(256) void att_logits_kernel(
    const ushort_t* __restrict__ hb, const float* __restrict__ att_src,
    const float* __restrict__ att_dst, float* __restrict__ a_src,
    float* __restrict__ a_dst) {
  int t = blockIdx.x * 256 + threadIdx.x;
  if (t >= N_NODES * NH) return;
  int n = t >> 2, hd = t & 3;
  const uint4* hp = (const uint4*)(hb + ((size_t)n << 7) + (hd << 5));
  const float* as = att_src + (hd << 5);
  const float* ad = att_dst + (hd << 5);
  float s1 = 0.f, s2 = 0.f;
#pragma unroll
  for (int q = 0; q < 4; q++) {
    uint4 hv = hp[q];
    float c0 = bf_lo(hv.x), c1 = bf_hi(hv.x);
    float c2 = bf_lo(hv.y), c3 = bf_hi(hv.y);
    float c4 = bf_lo(hv.z), c5 = bf_hi(hv.z);
    float c6 = bf_lo(hv.w), c7 = bf_hi(hv.w);
    float4 a0 = *(const float4*)(as + q * 8);
    float4 a1 = *(const float4*)(as + q * 8 + 4);
    float4 d0 = *(const float4*)(ad + q * 8);
    float4 d1 = *(const float4*)(ad + q * 8 + 4);
    s1 += c0*a0.x + c1*a0.y + c2*a0.z + c3*a0.w + c4*a1.x + c5*a1.y + c6*a1.z + c7*a1.w;
    s2 += c0*d0.x + c1*d0.y + c2*d0.z + c3*d0.w + c4*d1.x + c5*d1.y + c6*d1.z + c7*d1.w;
  }
  a_src[t] = s1;
  a_dst[t] = s2;
}

// ---------------- K3: degree count (round-4 proven) ----------------
__global__ __launch_bounds__(256) void deg_kernel(
    const int* __restrict__ ei, int* __restrict__ deg) {
  int e = blockIdx.x * 256 + threadIdx.x;
  if (e >= ETOT) return;
  int di = (e < E_EDGES) ? ei[E_EDGES + e] : (e - E_EDGES);
  atomicAdd(&deg[di], 1);
}

// ---------------- K4a/b/c: parallel exclusive scan (round-4 proven) -------
#define SCAN_NB ((N_NODES + 1023) / 1024)   // 49
__global__ __launch_bounds__(1024) void scan1_kernel(
    const int* __restrict__ deg, int* __restrict__ incl, int* __restrict__ part) {
  __shared__ int wsum[16];
  const int tid = threadIdx.x;
  const int wv = tid >> 6, ln = tid & 63;
  const int idx = blockIdx.x * 1024 + tid;
  int v = (idx < N_NODES) ? deg[idx] : 0;
  int xx = v;
#pragma unroll
  for (int off = 1; off < 64; off <<= 1) {
    int y = __shfl_up(xx, off, 64);
    if (ln >= off) xx += y;
  }
  if (ln == 63) wsum[wv] = xx;
  __syncthreads();
  if (tid < 16) {
    int ws = wsum[tid];
#pragma unroll
    for (int off = 1; off < 16; off <<= 1) {
      int y = __shfl_up(ws, off, 64);
      if (tid >= off) ws += y;
    }
    wsum[tid] = ws;
  }
  __syncthreads();
  int woff = (wv == 0) ? 0 : wsum[wv - 1];
  if (idx < N_NODES) incl[idx] = xx + woff;
  if (tid == 1023) part[blockIdx.x] = xx + woff;
}

__global__ __launch_bounds__(64) void scan2_kernel(int* __restrict__ part) {
  const int tid = threadIdx.x;
  int v = (tid < SCAN_NB) ? part[tid] : 0;
  int xx = v;
#pragma unroll
  for (int off = 1; off < 64; off <<= 1) {
    int y = __shfl_up(xx, off, 64);
    if (tid >= off) xx += y;
  }
  if (tid < SCAN_NB) part[tid] = xx - v;
}

__global__ __launch_bounds__(1024) void scan3_kernel(
    const int* __restrict__ incl, const int* __restrict__ part,
    int* __restrict__ row_start) {
  const int idx = blockIdx.x * 1024 + threadIdx.x;
  if (idx < N_NODES) row_start[idx + 1] = incl[idx] + part[blockIdx.x];
  if (idx == 0) row_start[0] = 0;
}

// ---------------- K5a: bucket edges (bucket = dst>>8, contiguous ranges) ---
// boff[b] == row_start[b<<8] since buckets are contiguous dst ranges.
#define BSZ   256
#define NBUCK ((N_NODES + BSZ - 1) / BSZ)       // 196
#define EPB_A 8192
#define NBLK_A ((ETOT + EPB_A - 1) / EPB_A)     // 202

__global__ __launch_bounds__(256) void binA_kernel(
    const int* __restrict__ ei, const int* __restrict__ row_start,
    int* __restrict__ gcur, uint_t* __restrict__ ebuf) {
  __shared__ int hist[NBUCK];
  __shared__ int base[NBUCK];
  const int tid = threadIdx.x;
  const int e0 = blockIdx.x * EPB_A;
  const int e1 = min(e0 + EPB_A, ETOT);
  for (int i = tid; i < NBUCK; i += 256) hist[i] = 0;
  __syncthreads();
  for (int e = e0 + tid; e < e1; e += 256) {
    int di = (e < E_EDGES) ? ei[E_EDGES + e] : (e - E_EDGES);
    atomicAdd(&hist[di >> 8], 1);
  }
  __syncthreads();
  for (int i = tid; i < NBUCK; i += 256) {
    int c = hist[i];
    base[i] = (c > 0) ? (row_start[i << 8] + atomicAdd(&gcur[i], c)) : 0;
    hist[i] = 0;
  }
  __syncthreads();
  for (int e = e0 + tid; e < e1; e += 256) {
    int si, di;
    if (e < E_EDGES) { si = ei[e]; di = ei[E_EDGES + e]; }
    else             { si = e - E_EDGES; di = si; }
    int b = di >> 8;
    int pos = base[b] + atomicAdd(&hist[b], 1);
    if (pos >= 0 && pos < ETOT)   // defensive: logic bug -> wrong, not fault
      ebuf[pos] = ((uint_t)(di & 255) << 24) | (uint_t)si;
  }
}

// ---------------- K5b: place within bucket (round-4 fill logic, local) -----
__global__ __launch_bounds__(256) void binB_kernel(
    const uint_t* __restrict__ ebuf, const int* __restrict__ row_start,
    int* __restrict__ deg, int* __restrict__ col) {
  const int b = blockIdx.x;
  const int n0 = b << 8;
  const int nend = min(n0 + BSZ, N_NODES);
  const int s0 = row_start[n0];
  const int s1 = row_start[nend];
  for (int i = s0 + threadIdx.x; i < s1; i += 256) {
    uint_t p = ebuf[i];
    int n = n0 + (int)(p >> 24);
    int si = (int)(p & 0xFFFFFFu);
    if (n < N_NODES) {
      int pos = atomicSub(&deg[n], 1) - 1;
      int q = row_start[n] + pos;
      if (q >= 0 && q < ETOT) col[q] = si;
    }
  }
}

// ---------------- K6: fused softmax + gather aggregation (round-4 proven) --
#define NPB 16
#define CH  16
#define MERGE(mv, sv)                                    \
  {                                                      \
    float mo_ = __shfl_xor(mv, off);                     \
    float so_ = __shfl_xor(sv, off);                     \
    float MM_ = fmaxf(mv, mo_);                          \
    sv = sv * __expf(mv - MM_) + so_ * __expf(mo_ - MM_);\
    mv = MM_;                                            \
  }

__global__ __launch_bounds__(256, 8) void agg_kernel(
    const int* __restrict__ col, const int* __restrict__ row_start,
    const ushort_t* __restrict__ hb, const float* __restrict__ a_src,
    const float* __restrict__ a_dst, float* __restrict__ out) {
  __shared__ float w_lds[NPB][CH][NH];   // 4 KB
  __shared__ int   si_lds[NPB][CH];      // 1 KB
  const int tid  = threadIdx.x;
  const int slot = tid >> 4;
  const int t    = tid & 15;
  const int node = blockIdx.x * NPB + slot;   // 3125*16 == N_NODES exactly
  const int start = row_start[node];
  const int deg   = row_start[node + 1] - start;
  const float4 ad = *(const float4*)(a_dst + (size_t)node * NH);

  float m0 = -1e30f, m1 = -1e30f, m2 = -1e30f, m3 = -1e30f;
  float s0 = 0.f, s1 = 0.f, s2 = 0.f, s3 = 0.f;
  for (int j = t; j < deg; j += 16) {
    int si = col[start + j];
    float4 as = *(const float4*)(a_src + (size_t)si * NH);
    float v0 = as.x + ad.x; v0 = v0 > 0.f ? v0 : 0.2f * v0;
    float v1 = as.y + ad.y; v1 = v1 > 0.f ? v1 : 0.2f * v1;
    float v2 = as.z + ad.z; v2 = v2 > 0.f ? v2 : 0.2f * v2;
    float v3 = as.w + ad.w; v3 = v3 > 0.f ? v3 : 0.2f * v3;
    float n0 = fmaxf(m0, v0); s0 = s0 * __expf(m0 - n0) + __expf(v0 - n0); m0 = n0;
    float n1 = fmaxf(m1, v1); s1 = s1 * __expf(m1 - n1) + __expf(v1 - n1); m1 = n1;
    float n2 = fmaxf(m2, v2); s2 = s2 * __expf(m2 - n2) + __expf(v2 - n2); m2 = n2;
    float n3 = fmaxf(m3, v3); s3 = s3 * __expf(m3 - n3) + __expf(v3 - n3); m3 = n3;
  }
#pragma unroll
  for (int off = 1; off < 16; off <<= 1) {
    MERGE(m0, s0) MERGE(m1, s1) MERGE(m2, s2) MERGE(m3, s3)
  }
  const float i0 = 1.f / s0, i1 = 1.f / s1, i2 = 1.f / s2, i3 = 1.f / s3;

  const int head = t >> 2;
  const int c8 = t << 3;
  const ushort_t* hc = hb + c8;
  float a0 = 0.f, a1 = 0.f, a2 = 0.f, a3 = 0.f;
  float a4 = 0.f, a5 = 0.f, a6 = 0.f, a7 = 0.f;

  for (int base_e = 0; base_e < deg; base_e += CH) {
    int nch = deg - base_e;
    if (nch > CH) nch = CH;
    if (t < nch) {
      int si = col[start + base_e + t];
      si_lds[slot][t] = si;
      float4 as = *(const float4*)(a_src + (size_t)si * NH);
      float v0 = as.x + ad.x; v0 = v0 > 0.f ? v0 : 0.2f * v0;
      float v1 = as.y + ad.y; v1 = v1 > 0.f ? v1 : 0.2f * v1;
      float v2 = as.z + ad.z; v2 = v2 > 0.f ? v2 : 0.2f * v2;
      float v3 = as.w + ad.w; v3 = v3 > 0.f ? v3 : 0.2f * v3;
      w_lds[slot][t][0] = __expf(v0 - m0) * i0 + 1.f;
      w_lds[slot][t][1] = __expf(v1 - m1) * i1 + 1.f;
      w_lds[slot][t][2] = __expf(v2 - m2) * i2 + 1.f;
      w_lds[slot][t][3] = __expf(v3 - m3) * i3 + 1.f;
    }
    __builtin_amdgcn_fence(__ATOMIC_ACQ_REL, "wavefront");
#pragma unroll 2
    for (int j = 0; j < nch; j++) {
      int si = si_lds[slot][j];
      float w = w_lds[slot][j][head];
      const uint4 hv = *(const uint4*)(hc + ((size_t)si << 7));
      a0 = fmaf(bf_lo(hv.x), w, a0);
      a1 = fmaf(bf_hi(hv.x), w, a1);
      a2 = fmaf(bf_lo(hv.y), w, a2);
      a3 = fmaf(bf_hi(hv.y), w, a3);
      a4 = fmaf(bf_lo(hv.z), w, a4);
      a5 = fmaf(bf_hi(hv.z), w, a5);
      a6 = fmaf(bf_lo(hv.w), w, a6);
      a7 = fmaf(bf_hi(hv.w), w, a7);
    }
    __builtin_amdgcn_fence(__ATOMIC_ACQ_REL, "wavefront");
  }
  float* op = out + ((size_t)node << 7) + c8;
  *(float4*)(op)     = make_float4(a0, a1, a2, a3);
  *(float4*)(op + 4) = make_float4(a4, a5, a6, a7);
}

extern "C" void kernel_launch(void* const* d_in, const int* in_sizes, int n_in,
                              void* d_out, int out_size, void* d_ws, size_t ws_size,
                              hipStream_t stream) {
  const float* x       = (const float*)d_in[0];
  const int*   ei      = (const int*)d_in[1];
  const float* W       = (const float*)d_in[2];
  const float* att_src = (const float*)d_in[3];
  const float* att_dst = (const float*)d_in[4];
  float* out = (float*)d_out;

  // ws: hb | a_src | a_dst | deg | gcur | row_start | incl | part | col | ebuf
  ushort_t* hb = (ushort_t*)d_ws;
  float* a_src = (float*)(hb + (size_t)N_NODES * DOUT);
  float* a_dst = a_src + (size_t)N_NODES * NH;
  int* deg       = (int*)(a_dst + (size_t)N_NODES * NH);  // N_NODES
  int* gcur      = deg + N_NODES;                         // NBUCK
  int* row_start = gcur + NBUCK;                          // N_NODES + 1
  int* incl      = row_start + N_NODES + 1;               // N_NODES
  int* part      = incl + N_NODES;                        // SCAN_NB
  int* col       = part + SCAN_NB;                        // ETOT
  uint_t* ebuf   = (uint_t*)(col + ETOT);                 // ETOT

  // zero deg + gcur in one shot (adjacent)
  hipMemsetAsync(deg, 0, (size_t)(N_NODES + NBUCK) * sizeof(int), stream);

  gemm_kernel<<<(N_NODES + 63) / 64, 512, 0, stream>>>(x, W, hb);
  att_logits_kernel<<<(N_NODES * NH + 255) / 256, 256, 0, stream>>>(
      hb, att_src, att_dst, a_src, a_dst);
  deg_kernel<<<(ETOT + 255) / 256, 256, 0, stream>>>(ei, deg);
  scan1_kernel<<<SCAN_NB, 1024, 0, stream>>>(deg, incl, part);
  scan2_kernel<<<1, 64, 0, stream>>>(part);
  scan3_kernel<<<SCAN_NB, 1024, 0, stream>>>(incl, part, row_start);
  binA_kernel<<<NBLK_A, 256, 0, stream>>>(ei, row_start, gcur, ebuf);
  binB_kernel<<<NBUCK, 256, 0, stream>>>(ebuf, row_start, deg, col);
  agg_kernel<<<N_NODES / NPB, 256, 0, stream>>>(col, row_start, hb, a_src, a_dst, out);
}

// Round 7
// 227.127 us; speedup vs baseline: 6.0556x; 1.3295x over previous
//
#include <hip/hip_runtime.h>

#define N_NODES 50000
#define E_EDGES 1600000
#define ETOT    (E_EDGES + N_NODES)
#define DIN  128
#define DOUT 128
#define NH   4
#define HD   32

typedef unsigned short ushort_t;
typedef unsigned int uint_t;

__device__ __forceinline__ ushort_t f2bf(float f) {
  uint_t u = __float_as_uint(f);
  u += 0x7fffu + ((u >> 16) & 1u);   // RNE
  return (ushort_t)(u >> 16);
}
__device__ __forceinline__ float bf_lo(uint_t u) {
  return __uint_as_float(u << 16);
}
__device__ __forceinline__ float bf_hi(uint_t u) {
  return __uint_as_float(u & 0xffff0000u);
}

// ---------------- K1: h = x @ W^T  (fp32 math, bf16 output) ----------------
// W staged k-chunk-major: Ws[kk][o][r] (word = kk*512 + o*4 + r). Lane c reads
// 16B at kk*512 + 4c -> 64 consecutive 16B words = conflict-free ds_read_b128.
__global__ __launch_bounds__(512, 4) void gemm_kernel(
    const float* __restrict__ x, const float* __restrict__ W,
    ushort_t* __restrict__ hb) {
  __shared__ float Ws[DIN * DOUT];  // 64 KB
  const int tid = threadIdx.x;
  for (int idx = tid; idx < DIN * DOUT; idx += 512) {
    int kk = idx >> 9;            // 0..31
    int o  = (idx >> 2) & 127;    // 0..127
    int r  = idx & 3;             // 0..3
    Ws[idx] = W[(o << 7) + (kk << 2) + r];
  }
  __syncthreads();

  const int g = tid >> 6;
  const int l = tid & 63;
  const int n0 = blockIdx.x * 64 + g * 8;
  const int c0 = l, c1 = l + 64;

  const float* xp[8];
#pragma unroll
  for (int i = 0; i < 8; i++) {
    int n = n0 + i;
    if (n >= N_NODES) n = N_NODES - 1;
    xp[i] = x + (size_t)n * DIN;
  }

  float acc0[8], acc1[8];
#pragma unroll
  for (int i = 0; i < 8; i++) { acc0[i] = 0.f; acc1[i] = 0.f; }

  for (int kk = 0; kk < 32; kk++) {
    const float* wrow = Ws + (kk << 9);
    const float4 wa = *(const float4*)(wrow + (c0 << 2));
    const float4 wb = *(const float4*)(wrow + (c1 << 2));
    const int k = kk << 2;
#pragma unroll
    for (int i = 0; i < 8; i++) {
      const float4 xv = *(const float4*)(xp[i] + k);
      acc0[i] = fmaf(xv.x, wa.x, acc0[i]);
      acc0[i] = fmaf(xv.y, wa.y, acc0[i]);
      acc0[i] = fmaf(xv.z, wa.z, acc0[i]);
      acc0[i] = fmaf(xv.w, wa.w, acc0[i]);
      acc1[i] = fmaf(xv.x, wb.x, acc1[i]);
      acc1[i] = fmaf(xv.y, wb.y, acc1[i]);
      acc1[i] = fmaf(xv.z, wb.z, acc1[i]);
      acc1[i] = fmaf(xv.w, wb.w, acc1[i]);
    }
  }
#pragma unroll
  for (int i = 0; i < 8; i++) {
    int n = n0 + i;
    if (n < N_NODES) {
      hb[((size_t)n << 7) + c0] = f2bf(acc0[i]);
      hb[((size_t)n << 7) + c1] = f2bf(acc1[i]);
    }
  }
}

// ---------------- K2: per-node attention logits (reads bf16 h) ------------
__global__ __launch_bounds__(256) void att_logits_kernel(
    const ushort_t* __restrict__ hb, const float* __restrict__ att_src,
    const float* __restrict__ att_dst, float* __restrict__ a_src,
    float* __restrict__ a_dst) {
  int t = blockIdx.x * 256 + threadIdx.x;
  if (t >= N_NODES * NH) return;
  int n = t >> 2, hd = t & 3;
  const uint4* hp = (const uint4*)(hb + ((size_t)n << 7) + (hd << 5));
  const float* as = att_src + (hd << 5);
  const float* ad = att_dst + (hd << 5);
  float s1 = 0.f, s2 = 0.f;
#pragma unroll
  for (int q = 0; q < 4; q++) {
    uint4 hv = hp[q];
    float c0 = bf_lo(hv.x), c1 = bf_hi(hv.x);
    float c2 = bf_lo(hv.y), c3 = bf_hi(hv.y);
    float c4 = bf_lo(hv.z), c5 = bf_hi(hv.z);
    float c6 = bf_lo(hv.w), c7 = bf_hi(hv.w);
    float4 a0 = *(const float4*)(as + q * 8);
    float4 a1 = *(const float4*)(as + q * 8 + 4);
    float4 d0 = *(const float4*)(ad + q * 8);
    float4 d1 = *(const float4*)(ad + q * 8 + 4);
    s1 += c0*a0.x + c1*a0.y + c2*a0.z + c3*a0.w + c4*a1.x + c5*a1.y + c6*a1.z + c7*a1.w;
    s2 += c0*d0.x + c1*d0.y + c2*d0.z + c3*d0.w + c4*d1.x + c5*d1.y + c6*d1.z + c7*d1.w;
  }
  a_src[t] = s1;
  a_dst[t] = s2;
}

// ---------------- CSR build: count -> scan -> place -> local build --------
#define BSZ   256
#define NBUCK ((N_NODES + BSZ - 1) / BSZ)       // 196
#define EPB_A 8192
#define NBLK_A ((ETOT + EPB_A - 1) / EPB_A)     // 202

// K3a: per-bucket edge counts (LDS-privatized histogram)
__global__ __launch_bounds__(256) void bcount_kernel(
    const int* __restrict__ ei, int* __restrict__ gcnt) {
  __shared__ int hist[NBUCK];
  const int tid = threadIdx.x;
  const int e0 = blockIdx.x * EPB_A;
  const int e1 = min(e0 + EPB_A, ETOT);
  for (int i = tid; i < NBUCK; i += 256) hist[i] = 0;
  __syncthreads();
  for (int e = e0 + tid; e < e1; e += 256) {
    int di = (e < E_EDGES) ? ei[E_EDGES + e] : (e - E_EDGES);
    atomicAdd(&hist[di >> 8], 1);
  }
  __syncthreads();
  for (int i = tid; i < NBUCK; i += 256) {
    int c = hist[i];
    if (c > 0) atomicAdd(&gcnt[i], c);
  }
}

// K3b: exclusive scan of 196 bucket counts -> boff[0..NBUCK]
__global__ __launch_bounds__(256) void bscan_kernel(
    const int* __restrict__ gcnt, int* __restrict__ boff) {
  __shared__ int wsum[4];
  const int tid = threadIdx.x;
  const int ln = tid & 63, wv = tid >> 6;
  int v = (tid < NBUCK) ? gcnt[tid] : 0;
  int xx = v;
#pragma unroll
  for (int off = 1; off < 64; off <<= 1) {
    int y = __shfl_up(xx, off, 64);
    if (ln >= off) xx += y;
  }
  if (ln == 63) wsum[wv] = xx;
  __syncthreads();
  if (tid < 4) {
    int w = wsum[tid];
#pragma unroll
    for (int off = 1; off < 4; off <<= 1) {
      int y = __shfl_up(w, off, 64);
      if (tid >= off) w += y;
    }
    wsum[tid] = w;
  }
  __syncthreads();
  int wo = (wv == 0) ? 0 : wsum[wv - 1];
  if (tid < NBUCK) boff[tid] = xx + wo - v;       // exclusive
  if (tid == NBUCK - 1) boff[NBUCK] = xx + wo;    // == ETOT
}

// K3c: bin edges into bucket regions of ebuf; packed (dst&255)<<24 | src
__global__ __launch_bounds__(256) void binA_kernel(
    const int* __restrict__ ei, const int* __restrict__ boff,
    int* __restrict__ gcur, uint_t* __restrict__ ebuf) {
  __shared__ int hist[NBUCK];
  __shared__ int base[NBUCK];
  const int tid = threadIdx.x;
  const int e0 = blockIdx.x * EPB_A;
  const int e1 = min(e0 + EPB_A, ETOT);
  for (int i = tid; i < NBUCK; i += 256) hist[i] = 0;
  __syncthreads();
  for (int e = e0 + tid; e < e1; e += 256) {
    int di = (e < E_EDGES) ? ei[E_EDGES + e] : (e - E_EDGES);
    atomicAdd(&hist[di >> 8], 1);
  }
  __syncthreads();
  for (int i = tid; i < NBUCK; i += 256) {
    int c = hist[i];
    base[i] = (c > 0) ? (boff[i] + atomicAdd(&gcur[i], c)) : 0;
    hist[i] = 0;
  }
  __syncthreads();
  for (int e = e0 + tid; e < e1; e += 256) {
    int si, di;
    if (e < E_EDGES) { si = ei[e]; di = ei[E_EDGES + e]; }
    else             { si = e - E_EDGES; di = si; }
    int b = di >> 8;
    int pos = base[b] + atomicAdd(&hist[b], 1);
    if (pos >= 0 && pos < ETOT)   // defensive
      ebuf[pos] = ((uint_t)(di & 255) << 24) | (uint_t)si;
  }
}

// K3d: per-bucket node degrees + local scan -> row_start; place col.
__global__ __launch_bounds__(256) void binB_kernel(
    const uint_t* __restrict__ ebuf, const int* __restrict__ boff,
    int* __restrict__ row_start, int* __restrict__ col) {
  __shared__ int cnt[BSZ];
  __shared__ int roff[BSZ];
  __shared__ int wsum2[4];
  const int b = blockIdx.x;
  const int tid = threadIdx.x;
  const int ln = tid & 63, wv = tid >> 6;
  const int n0 = b << 8;
  const int nn = min(BSZ, N_NODES - n0);
  const int s0 = boff[b], s1 = boff[b + 1];
  cnt[tid] = 0;
  __syncthreads();
  for (int i = s0 + tid; i < s1; i += 256)
    atomicAdd(&cnt[ebuf[i] >> 24], 1);
  __syncthreads();
  int v = cnt[tid];
  int xx = v;
#pragma unroll
  for (int off = 1; off < 64; off <<= 1) {
    int y = __shfl_up(xx, off, 64);
    if (ln >= off) xx += y;
  }
  if (ln == 63) wsum2[wv] = xx;
  __syncthreads();
  if (tid < 4) {
    int w = wsum2[tid];
#pragma unroll
    for (int off = 1; off < 4; off <<= 1) {
      int y = __shfl_up(w, off, 64);
      if (tid >= off) w += y;
    }
    wsum2[tid] = w;
  }
  __syncthreads();
  int wo = (wv == 0) ? 0 : wsum2[wv - 1];
  roff[tid] = xx + wo - v;                           // exclusive
  if (tid < nn) row_start[n0 + tid + 1] = s0 + xx + wo;  // inclusive end
  if (b == 0 && tid == 0) row_start[0] = 0;
  __syncthreads();
  cnt[tid] = 0;
  __syncthreads();
  for (int i = s0 + tid; i < s1; i += 256) {
    uint_t p = ebuf[i];
    int ld = p >> 24;
    int pos = atomicAdd(&cnt[ld], 1);
    int q = s0 + roff[ld] + pos;
    if (q >= 0 && q < ETOT) col[q] = (int)(p & 0xFFFFFFu);
  }
}

// ---------------- K6: fused softmax + gather aggregation (bf16 h) ----------
#define NPB 16
#define CH  16
#define MERGE(mv, sv)                                    \
  {                                                      \
    float mo_ = __shfl_xor(mv, off);                     \
    float so_ = __shfl_xor(sv, off);                     \
    float MM_ = fmaxf(mv, mo_);                          \
    sv = sv * __expf(mv - MM_) + so_ * __expf(mo_ - MM_);\
    mv = MM_;                                            \
  }

__global__ __launch_bounds__(256, 8) void agg_kernel(
    const int* __restrict__ col, const int* __restrict__ row_start,
    const ushort_t* __restrict__ hb, const float* __restrict__ a_src,
    const float* __restrict__ a_dst, float* __restrict__ out) {
  __shared__ float w_lds[NPB][CH][NH];   // 4 KB
  __shared__ int   si_lds[NPB][CH];      // 1 KB
  const int tid  = threadIdx.x;
  const int slot = tid >> 4;
  const int t    = tid & 15;
  const int node = blockIdx.x * NPB + slot;   // 3125*16 == N_NODES exactly
  const int start = row_start[node];
  const int deg   = row_start[node + 1] - start;
  const float4 ad = *(const float4*)(a_dst + (size_t)node * NH);

  float m0 = -1e30f, m1 = -1e30f, m2 = -1e30f, m3 = -1e30f;
  float s0 = 0.f, s1 = 0.f, s2 = 0.f, s3 = 0.f;
  for (int j = t; j < deg; j += 16) {
    int si = col[start + j];
    si = si < N_NODES ? si : 0;   // defensive clamp (bug -> wrong, not fault)
    float4 as = *(const float4*)(a_src + (size_t)si * NH);
    float v0 = as.x + ad.x; v0 = v0 > 0.f ? v0 : 0.2f * v0;
    float v1 = as.y + ad.y; v1 = v1 > 0.f ? v1 : 0.2f * v1;
    float v2 = as.z + ad.z; v2 = v2 > 0.f ? v2 : 0.2f * v2;
    float v3 = as.w + ad.w; v3 = v3 > 0.f ? v3 : 0.2f * v3;
    float n0 = fmaxf(m0, v0); s0 = s0 * __expf(m0 - n0) + __expf(v0 - n0); m0 = n0;
    float n1 = fmaxf(m1, v1); s1 = s1 * __expf(m1 - n1) + __expf(v1 - n1); m1 = n1;
    float n2 = fmaxf(m2, v2); s2 = s2 * __expf(m2 - n2) + __expf(v2 - n2); m2 = n2;
    float n3 = fmaxf(m3, v3); s3 = s3 * __expf(m3 - n3) + __expf(v3 - n3); m3 = n3;
  }
#pragma unroll
  for (int off = 1; off < 16; off <<= 1) {
    MERGE(m0, s0) MERGE(m1, s1) MERGE(m2, s2) MERGE(m3, s3)
  }
  const float i0 = 1.f / s0, i1 = 1.f / s1, i2 = 1.f / s2, i3 = 1.f / s3;

  const int head = t >> 2;
  const int c8 = t << 3;
  const ushort_t* hc = hb + c8;
  float a0 = 0.f, a1 = 0.f, a2 = 0.f, a3 = 0.f;
  float a4 = 0.f, a5 = 0.f, a6 = 0.f, a7 = 0.f;

  for (int base_e = 0; base_e < deg; base_e += CH) {
    int nch = deg - base_e;
    if (nch > CH) nch = CH;
    if (t < nch) {
      int si = col[start + base_e + t];
      si = si < N_NODES ? si : 0;   // defensive clamp
      si_lds[slot][t] = si;
      float4 as = *(const float4*)(a_src + (size_t)si * NH);
      float v0 = as.x + ad.x; v0 = v0 > 0.f ? v0 : 0.2f * v0;
      float v1 = as.y + ad.y; v1 = v1 > 0.f ? v1 : 0.2f * v1;
      float v2 = as.z + ad.z; v2 = v2 > 0.f ? v2 : 0.2f * v2;
      float v3 = as.w + ad.w; v3 = v3 > 0.f ? v3 : 0.2f * v3;
      w_lds[slot][t][0] = __expf(v0 - m0) * i0 + 1.f;
      w_lds[slot][t][1] = __expf(v1 - m1) * i1 + 1.f;
      w_lds[slot][t][2] = __expf(v2 - m2) * i2 + 1.f;
      w_lds[slot][t][3] = __expf(v3 - m3) * i3 + 1.f;
    }
    __builtin_amdgcn_fence(__ATOMIC_ACQ_REL, "wavefront");
#pragma unroll 2
    for (int j = 0; j < nch; j++) {
      int si = si_lds[slot][j];
      float w = w_lds[slot][j][head];
      const uint4 hv = *(const uint4*)(hc + ((size_t)si << 7));
      a0 = fmaf(bf_lo(hv.x), w, a0);
      a1 = fmaf(bf_hi(hv.x), w, a1);
      a2 = fmaf(bf_lo(hv.y), w, a2);
      a3 = fmaf(bf_hi(hv.y), w, a3);
      a4 = fmaf(bf_lo(hv.z), w, a4);
      a5 = fmaf(bf_hi(hv.z), w, a5);
      a6 = fmaf(bf_lo(hv.w), w, a6);
      a7 = fmaf(bf_hi(hv.w), w, a7);
    }
    __builtin_amdgcn_fence(__ATOMIC_ACQ_REL, "wavefront");
  }
  float* op = out + ((size_t)node << 7) + c8;
  *(float4*)(op)     = make_float4(a0, a1, a2, a3);
  *(float4*)(op + 4) = make_float4(a4, a5, a6, a7);
}

extern "C" void kernel_launch(void* const* d_in, const int* in_sizes, int n_in,
                              void* d_out, int out_size, void* d_ws, size_t ws_size,
                              hipStream_t stream) {
  const float* x       = (const float*)d_in[0];
  const int*   ei      = (const int*)d_in[1];
  const float* W       = (const float*)d_in[2];
  const float* att_src = (const float*)d_in[3];
  const float* att_dst = (const float*)d_in[4];
  float* out = (float*)d_out;

  // ws: hb | a_src | a_dst | gcnt | gcur | boff | row_start | col | ebuf
  ushort_t* hb = (ushort_t*)d_ws;
  float* a_src = (float*)(hb + (size_t)N_NODES * DOUT);
  float* a_dst = a_src + (size_t)N_NODES * NH;
  int* gcnt      = (int*)(a_dst + (size_t)N_NODES * NH);  // NBUCK
  int* gcur      = gcnt + NBUCK;                          // NBUCK
  int* boff      = gcur + NBUCK;                          // NBUCK + 1
  int* row_start = boff + NBUCK + 1;                      // N_NODES + 1
  int* col       = row_start + N_NODES + 1;               // ETOT
  uint_t* ebuf   = (uint_t*)(col + ETOT);                 // ETOT

  // zero gcnt + gcur in one shot (adjacent)
  hipMemsetAsync(gcnt, 0, (size_t)2 * NBUCK * sizeof(int), stream);

  bcount_kernel<<<NBLK_A, 256, 0, stream>>>(ei, gcnt);
  bscan_kernel<<<1, 256, 0, stream>>>(gcnt, boff);
  binA_kernel<<<NBLK_A, 256, 0, stream>>>(ei, boff, gcur, ebuf);
  binB_kernel<<<NBUCK, 256, 0, stream>>>(ebuf, boff, row_start, col);
  gemm_kernel<<<(N_NODES + 63) / 64, 512, 0, stream>>>(x, W, hb);
  att_logits_kernel<<<(N_NODES * NH + 255) / 256, 256, 0, stream>>>(
      hb, att_src, att_dst, a_src, a_dst);
  agg_kernel<<<N_NODES / NPB, 256, 0, stream>>>(col, row_start, hb, a_src, a_dst, out);
}

// Round 8
// 175.037 us; speedup vs baseline: 7.8577x; 1.2976x over previous
//
#include <hip/hip_runtime.h>

#define N_NODES 50000
#define E_EDGES 1600000
#define ETOT    (E_EDGES + N_NODES)
#define DIN  128
#define DOUT 128
#define NH   4
#define HD   32

typedef unsigned short ushort_t;
typedef unsigned int uint_t;
typedef __attribute__((ext_vector_type(8))) short bfrag;   // 8 bf16 (4 VGPRs)
typedef __attribute__((ext_vector_type(4))) float ffrag;   // 4 fp32 acc

__device__ __forceinline__ ushort_t f2bf(float f) {
  uint_t u = __float_as_uint(f);
  u += 0x7fffu + ((u >> 16) & 1u);   // RNE
  return (ushort_t)(u >> 16);
}
__device__ __forceinline__ float bf_lo(uint_t u) {
  return __uint_as_float(u << 16);
}
__device__ __forceinline__ float bf_hi(uint_t u) {
  return __uint_as_float(u & 0xffff0000u);
}

// ---------------- K0: fp32 -> bf16 cast (x and W) ----------------
__global__ __launch_bounds__(256) void cast_kernel(
    const float* __restrict__ src, ushort_t* __restrict__ dst, int ngroups) {
  int i = blockIdx.x * 256 + threadIdx.x;   // group of 4 floats
  if (i >= ngroups) return;
  float4 v = ((const float4*)src)[i];
  ushort4 o;
  o.x = f2bf(v.x); o.y = f2bf(v.y); o.z = f2bf(v.z); o.w = f2bf(v.w);
  ((ushort4*)dst)[i] = o;
}

// ---------------- K1: h = xb @ Wb^T via MFMA (bf16 in, bf16 out) ----------
// Block 256 = 4 waves; wave handles 16 nodes x 128 outputs.
// A frag: xb[n = base + (l&15)][kt*32 + (l>>4)*8 .. +8]   (16B contiguous)
// B frag: Wb[o = oc*16 + (l&15)][kt*32 + (l>>4)*8 .. +8]  (16B contiguous)
// Wb staged in LDS as 16B units, unit u stored at u^(row&7) -> <=2-way reads.
// D: node = base + (l>>4)*4 + reg, o = oc*16 + (l&15)   [m89-verified layout]
__global__ __launch_bounds__(256, 4) void gemm_mfma_kernel(
    const ushort_t* __restrict__ xb, const ushort_t* __restrict__ Wb,
    ushort_t* __restrict__ hb) {
  __shared__ ushort_t Ws[DIN * DOUT];   // 32 KB bf16
  const int tid = threadIdx.x;
  // stage W: 2048 16B-units; row = u>>4 (16 units per 256B row)
  for (int u = tid; u < 2048; u += 256) {
    int row = u >> 4;
    *(uint4*)&Ws[(u ^ (row & 7)) * 8] = *(const uint4*)&Wb[u * 8];
  }
  __syncthreads();

  const int wv = tid >> 6, l = tid & 63;
  const int lr = l & 15, lg = l >> 4;
  const int nbase = blockIdx.x * 64 + wv * 16;
  int na = nbase + lr;
  if (na >= N_NODES) na = N_NODES - 1;   // clamp A loads; stores guarded

  ffrag acc[8];
#pragma unroll
  for (int oc = 0; oc < 8; oc++) acc[oc] = (ffrag){0.f, 0.f, 0.f, 0.f};

#pragma unroll
  for (int kt = 0; kt < 4; kt++) {
    const bfrag a = *(const bfrag*)&xb[((size_t)na << 7) + kt * 32 + lg * 8];
#pragma unroll
    for (int oc = 0; oc < 8; oc++) {
      const int u = ((oc * 16 + lr) << 4) + kt * 4 + lg;   // 16B unit
      const bfrag b = *(const bfrag*)&Ws[(u ^ (lr & 7)) * 8];
      acc[oc] = __builtin_amdgcn_mfma_f32_16x16x32_bf16(a, b, acc[oc], 0, 0, 0);
    }
  }

#pragma unroll
  for (int oc = 0; oc < 8; oc++) {
#pragma unroll
    for (int j = 0; j < 4; j++) {
      int n = nbase + lg * 4 + j;
      if (n < N_NODES)
        hb[((size_t)n << 7) + oc * 16 + lr] = f2bf(acc[oc][j]);
    }
  }
}

// ---------------- K2: per-node attention logits (reads bf16 h) ------------
__global__ __launch_bounds__(256) void att_logits_kernel(
    const ushort_t* __restrict__ hb, const float* __restrict__ att_src,
    const float* __restrict__ att_dst, float* __restrict__ a_src,
    float* __restrict__ a_dst) {
  int t = blockIdx.x * 256 + threadIdx.x;
  if (t >= N_NODES * NH) return;
  int n = t >> 2, hd = t & 3;
  const uint4* hp = (const uint4*)(hb + ((size_t)n << 7) + (hd << 5));
  const float* as = att_src + (hd << 5);
  const float* ad = att_dst + (hd << 5);
  float s1 = 0.f, s2 = 0.f;
#pragma unroll
  for (int q = 0; q < 4; q++) {
    uint4 hv = hp[q];
    float c0 = bf_lo(hv.x), c1 = bf_hi(hv.x);
    float c2 = bf_lo(hv.y), c3 = bf_hi(hv.y);
    float c4 = bf_lo(hv.z), c5 = bf_hi(hv.z);
    float c6 = bf_lo(hv.w), c7 = bf_hi(hv.w);
    float4 a0 = *(const float4*)(as + q * 8);
    float4 a1 = *(const float4*)(as + q * 8 + 4);
    float4 d0 = *(const float4*)(ad + q * 8);
    float4 d1 = *(const float4*)(ad + q * 8 + 4);
    s1 += c0*a0.x + c1*a0.y + c2*a0.z + c3*a0.w + c4*a1.x + c5*a1.y + c6*a1.z + c7*a1.w;
    s2 += c0*d0.x + c1*d0.y + c2*d0.z + c3*d0.w + c4*d1.x + c5*d1.y + c6*d1.z + c7*d1.w;
  }
  a_src[t] = s1;
  a_dst[t] = s2;
}

// ---------------- CSR build (round-7 proven, unchanged) ----------------
#define BSZ   256
#define NBUCK ((N_NODES + BSZ - 1) / BSZ)       // 196
#define EPB_A 8192
#define NBLK_A ((ETOT + EPB_A - 1) / EPB_A)     // 202

__global__ __launch_bounds__(256) void bcount_kernel(
    const int* __restrict__ ei, int* __restrict__ gcnt) {
  __shared__ int hist[NBUCK];
  const int tid = threadIdx.x;
  const int e0 = blockIdx.x * EPB_A;
  const int e1 = min(e0 + EPB_A, ETOT);
  for (int i = tid; i < NBUCK; i += 256) hist[i] = 0;
  __syncthreads();
  for (int e = e0 + tid; e < e1; e += 256) {
    int di = (e < E_EDGES) ? ei[E_EDGES + e] : (e - E_EDGES);
    atomicAdd(&hist[di >> 8], 1);
  }
  __syncthreads();
  for (int i = tid; i < NBUCK; i += 256) {
    int c = hist[i];
    if (c > 0) atomicAdd(&gcnt[i], c);
  }
}

__global__ __launch_bounds__(256) void bscan_kernel(
    const int* __restrict__ gcnt, int* __restrict__ boff) {
  __shared__ int wsum[4];
  const int tid = threadIdx.x;
  const int ln = tid & 63, wv = tid >> 6;
  int v = (tid < NBUCK) ? gcnt[tid] : 0;
  int xx = v;
#pragma unroll
  for (int off = 1; off < 64; off <<= 1) {
    int y = __shfl_up(xx, off, 64);
    if (ln >= off) xx += y;
  }
  if (ln == 63) wsum[wv] = xx;
  __syncthreads();
  if (tid < 4) {
    int w = wsum[tid];
#pragma unroll
    for (int off = 1; off < 4; off <<= 1) {
      int y = __shfl_up(w, off, 64);
      if (tid >= off) w += y;
    }
    wsum[tid] = w;
  }
  __syncthreads();
  int wo = (wv == 0) ? 0 : wsum[wv - 1];
  if (tid < NBUCK) boff[tid] = xx + wo - v;
  if (tid == NBUCK - 1) boff[NBUCK] = xx + wo;
}

__global__ __launch_bounds__(256) void binA_kernel(
    const int* __restrict__ ei, const int* __restrict__ boff,
    int* __restrict__ gcur, uint_t* __restrict__ ebuf) {
  __shared__ int hist[NBUCK];
  __shared__ int base[NBUCK];
  const int tid = threadIdx.x;
  const int e0 = blockIdx.x * EPB_A;
  const int e1 = min(e0 + EPB_A, ETOT);
  for (int i = tid; i < NBUCK; i += 256) hist[i] = 0;
  __syncthreads();
  for (int e = e0 + tid; e < e1; e += 256) {
    int di = (e < E_EDGES) ? ei[E_EDGES + e] : (e - E_EDGES);
    atomicAdd(&hist[di >> 8], 1);
  }
  __syncthreads();
  for (int i = tid; i < NBUCK; i += 256) {
    int c = hist[i];
    base[i] = (c > 0) ? (boff[i] + atomicAdd(&gcur[i], c)) : 0;
    hist[i] = 0;
  }
  __syncthreads();
  for (int e = e0 + tid; e < e1; e += 256) {
    int si, di;
    if (e < E_EDGES) { si = ei[e]; di = ei[E_EDGES + e]; }
    else             { si = e - E_EDGES; di = si; }
    int b = di >> 8;
    int pos = base[b] + atomicAdd(&hist[b], 1);
    if (pos >= 0 && pos < ETOT)
      ebuf[pos] = ((uint_t)(di & 255) << 24) | (uint_t)si;
  }
}

__global__ __launch_bounds__(256) void binB_kernel(
    const uint_t* __restrict__ ebuf, const int* __restrict__ boff,
    int* __restrict__ row_start, int* __restrict__ col) {
  __shared__ int cnt[BSZ];
  __shared__ int roff[BSZ];
  __shared__ int wsum2[4];
  const int b = blockIdx.x;
  const int tid = threadIdx.x;
  const int ln = tid & 63, wv = tid >> 6;
  const int n0 = b << 8;
  const int nn = min(BSZ, N_NODES - n0);
  const int s0 = boff[b], s1 = boff[b + 1];
  cnt[tid] = 0;
  __syncthreads();
  for (int i = s0 + tid; i < s1; i += 256)
    atomicAdd(&cnt[ebuf[i] >> 24], 1);
  __syncthreads();
  int v = cnt[tid];
  int xx = v;
#pragma unroll
  for (int off = 1; off < 64; off <<= 1) {
    int y = __shfl_up(xx, off, 64);
    if (ln >= off) xx += y;
  }
  if (ln == 63) wsum2[wv] = xx;
  __syncthreads();
  if (tid < 4) {
    int w = wsum2[tid];
#pragma unroll
    for (int off = 1; off < 4; off <<= 1) {
      int y = __shfl_up(w, off, 64);
      if (tid >= off) w += y;
    }
    wsum2[tid] = w;
  }
  __syncthreads();
  int wo = (wv == 0) ? 0 : wsum2[wv - 1];
  roff[tid] = xx + wo - v;
  if (tid < nn) row_start[n0 + tid + 1] = s0 + xx + wo;
  if (b == 0 && tid == 0) row_start[0] = 0;
  __syncthreads();
  cnt[tid] = 0;
  __syncthreads();
  for (int i = s0 + tid; i < s1; i += 256) {
    uint_t p = ebuf[i];
    int ld = p >> 24;
    int pos = atomicAdd(&cnt[ld], 1);
    int q = s0 + roff[ld] + pos;
    if (q >= 0 && q < ETOT) col[q] = (int)(p & 0xFFFFFFu);
  }
}

// ---------------- K6: fused softmax + gather aggregation (round-7 proven) --
#define NPB 16
#define CH  16
#define MERGE(mv, sv)                                    \
  {                                                      \
    float mo_ = __shfl_xor(mv, off);                     \
    float so_ = __shfl_xor(sv, off);                     \
    float MM_ = fmaxf(mv, mo_);                          \
    sv = sv * __expf(mv - MM_) + so_ * __expf(mo_ - MM_);\
    mv = MM_;                                            \
  }

__global__ __launch_bounds__(256, 8) void agg_kernel(
    const int* __restrict__ col, const int* __restrict__ row_start,
    const ushort_t* __restrict__ hb, const float* __restrict__ a_src,
    const float* __restrict__ a_dst, float* __restrict__ out) {
  __shared__ float w_lds[NPB][CH][NH];   // 4 KB
  __shared__ int   si_lds[NPB][CH];      // 1 KB
  const int tid  = threadIdx.x;
  const int slot = tid >> 4;
  const int t    = tid & 15;
  const int node = blockIdx.x * NPB + slot;
  const int start = row_start[node];
  const int deg   = row_start[node + 1] - start;
  const float4 ad = *(const float4*)(a_dst + (size_t)node * NH);

  float m0 = -1e30f, m1 = -1e30f, m2 = -1e30f, m3 = -1e30f;
  float s0 = 0.f, s1 = 0.f, s2 = 0.f, s3 = 0.f;
  for (int j = t; j < deg; j += 16) {
    int si = col[start + j];
    si = si < N_NODES ? si : 0;
    float4 as = *(const float4*)(a_src + (size_t)si * NH);
    float v0 = as.x + ad.x; v0 = v0 > 0.f ? v0 : 0.2f * v0;
    float v1 = as.y + ad.y; v1 = v1 > 0.f ? v1 : 0.2f * v1;
    float v2 = as.z + ad.z; v2 = v2 > 0.f ? v2 : 0.2f * v2;
    float v3 = as.w + ad.w; v3 = v3 > 0.f ? v3 : 0.2f * v3;
    float n0 = fmaxf(m0, v0); s0 = s0 * __expf(m0 - n0) + __expf(v0 - n0); m0 = n0;
    float n1 = fmaxf(m1, v1); s1 = s1 * __expf(m1 - n1) + __expf(v1 - n1); m1 = n1;
    float n2 = fmaxf(m2, v2); s2 = s2 * __expf(m2 - n2) + __expf(v2 - n2); m2 = n2;
    float n3 = fmaxf(m3, v3); s3 = s3 * __expf(m3 - n3) + __expf(v3 - n3); m3 = n3;
  }
#pragma unroll
  for (int off = 1; off < 16; off <<= 1) {
    MERGE(m0, s0) MERGE(m1, s1) MERGE(m2, s2) MERGE(m3, s3)
  }
  const float i0 = 1.f / s0, i1 = 1.f / s1, i2 = 1.f / s2, i3 = 1.f / s3;

  const int head = t >> 2;
  const int c8 = t << 3;
  const ushort_t* hc = hb + c8;
  float a0 = 0.f, a1 = 0.f, a2 = 0.f, a3 = 0.f;
  float a4 = 0.f, a5 = 0.f, a6 = 0.f, a7 = 0.f;

  for (int base_e = 0; base_e < deg; base_e += CH) {
    int nch = deg - base_e;
    if (nch > CH) nch = CH;
    if (t < nch) {
      int si = col[start + base_e + t];
      si = si < N_NODES ? si : 0;
      si_lds[slot][t] = si;
      float4 as = *(const float4*)(a_src + (size_t)si * NH);
      float v0 = as.x + ad.x; v0 = v0 > 0.f ? v0 : 0.2f * v0;
      float v1 = as.y + ad.y; v1 = v1 > 0.f ? v1 : 0.2f * v1;
      float v2 = as.z + ad.z; v2 = v2 > 0.f ? v2 : 0.2f * v2;
      float v3 = as.w + ad.w; v3 = v3 > 0.f ? v3 : 0.2f * v3;
      w_lds[slot][t][0] = __expf(v0 - m0) * i0 + 1.f;
      w_lds[slot][t][1] = __expf(v1 - m1) * i1 + 1.f;
      w_lds[slot][t][2] = __expf(v2 - m2) * i2 + 1.f;
      w_lds[slot][t][3] = __expf(v3 - m3) * i3 + 1.f;
    }
    __builtin_amdgcn_fence(__ATOMIC_ACQ_REL, "wavefront");
#pragma unroll 2
    for (int j = 0; j < nch; j++) {
      int si = si_lds[slot][j];
      float w = w_lds[slot][j][head];
      const uint4 hv = *(const uint4*)(hc + ((size_t)si << 7));
      a0 = fmaf(bf_lo(hv.x), w, a0);
      a1 = fmaf(bf_hi(hv.x), w, a1);
      a2 = fmaf(bf_lo(hv.y), w, a2);
      a3 = fmaf(bf_hi(hv.y), w, a3);
      a4 = fmaf(bf_lo(hv.z), w, a4);
      a5 = fmaf(bf_hi(hv.z), w, a5);
      a6 = fmaf(bf_lo(hv.w), w, a6);
      a7 = fmaf(bf_hi(hv.w), w, a7);
    }
    __builtin_amdgcn_fence(__ATOMIC_ACQ_REL, "wavefront");
  }
  float* op = out + ((size_t)node << 7) + c8;
  *(float4*)(op)     = make_float4(a0, a1, a2, a3);
  *(float4*)(op + 4) = make_float4(a4, a5, a6, a7);
}

extern "C" void kernel_launch(void* const* d_in, const int* in_sizes, int n_in,
                              void* d_out, int out_size, void* d_ws, size_t ws_size,
                              hipStream_t stream) {
  const float* x       = (const float*)d_in[0];
  const int*   ei      = (const int*)d_in[1];
  const float* W       = (const float*)d_in[2];
  const float* att_src = (const float*)d_in[3];
  const float* att_dst = (const float*)d_in[4];
  float* out = (float*)d_out;

  // ws: hb | xb | Wb | a_src | a_dst | gcnt | gcur | boff | row_start | col | ebuf
  ushort_t* hb = (ushort_t*)d_ws;
  ushort_t* xb = hb + (size_t)N_NODES * DOUT;
  ushort_t* Wb = xb + (size_t)N_NODES * DIN;
  float* a_src = (float*)(Wb + DIN * DOUT);
  float* a_dst = a_src + (size_t)N_NODES * NH;
  int* gcnt      = (int*)(a_dst + (size_t)N_NODES * NH);  // NBUCK
  int* gcur      = gcnt + NBUCK;                          // NBUCK
  int* boff      = gcur + NBUCK;                          // NBUCK + 1
  int* row_start = boff + NBUCK + 1;                      // N_NODES + 1
  int* col       = row_start + N_NODES + 1;               // ETOT
  uint_t* ebuf   = (uint_t*)(col + ETOT);                 // ETOT

  hipMemsetAsync(gcnt, 0, (size_t)2 * NBUCK * sizeof(int), stream);

  cast_kernel<<<(N_NODES * DIN / 4 + 255) / 256, 256, 0, stream>>>(
      x, xb, N_NODES * DIN / 4);
  cast_kernel<<<(DIN * DOUT / 4 + 255) / 256, 256, 0, stream>>>(
      W, Wb, DIN * DOUT / 4);
  gemm_mfma_kernel<<<(N_NODES + 63) / 64, 256, 0, stream>>>(xb, Wb, hb);
  att_logits_kernel<<<(N_NODES * NH + 255) / 256, 256, 0, stream>>>(
      hb, att_src, att_dst, a_src, a_dst);
  bcount_kernel<<<NBLK_A, 256, 0, stream>>>(ei, gcnt);
  bscan_kernel<<<1, 256, 0, stream>>>(gcnt, boff);
  binA_kernel<<<NBLK_A, 256, 0, stream>>>(ei, boff, gcur, ebuf);
  binB_kernel<<<NBUCK, 256, 0, stream>>>(ebuf, boff, row_start, col);
  agg_kernel<<<N_NODES / NPB, 256, 0, stream>>>(col, row_start, hb, a_src, a_dst, out);
}

// Round 9
// 164.531 us; speedup vs baseline: 8.3595x; 1.0639x over previous
//
#include <hip/hip_runtime.h>

#define N_NODES 50000
#define E_EDGES 1600000
#define ETOT    (E_EDGES + N_NODES)
#define DIN  128
#define DOUT 128
#define NH   4
#define HD   32

typedef unsigned short ushort_t;
typedef unsigned int uint_t;
typedef __attribute__((ext_vector_type(8))) short bfrag;   // 8 bf16 (4 VGPRs)
typedef __attribute__((ext_vector_type(4))) float ffrag;   // 4 fp32 acc

__device__ __forceinline__ ushort_t f2bf(float f) {
  uint_t u = __float_as_uint(f);
  u += 0x7fffu + ((u >> 16) & 1u);   // RNE
  return (ushort_t)(u >> 16);
}
__device__ __forceinline__ float bf_lo(uint_t u) {
  return __uint_as_float(u << 16);
}
__device__ __forceinline__ float bf_hi(uint_t u) {
  return __uint_as_float(u & 0xffff0000u);
}

// ---------------- K0: fp32 -> bf16 cast (x and W) ----------------
__global__ __launch_bounds__(256) void cast_kernel(
    const float* __restrict__ src, ushort_t* __restrict__ dst, int ngroups) {
  int i = blockIdx.x * 256 + threadIdx.x;   // group of 4 floats
  if (i >= ngroups) return;
  float4 v = ((const float4*)src)[i];
  ushort4 o;
  o.x = f2bf(v.x); o.y = f2bf(v.y); o.z = f2bf(v.z); o.w = f2bf(v.w);
  ((ushort4*)dst)[i] = o;
}

// ---------------- K1: h = xb @ Wb^T via MFMA (round-8 proven) --------------
__global__ __launch_bounds__(256, 4) void gemm_mfma_kernel(
    const ushort_t* __restrict__ xb, const ushort_t* __restrict__ Wb,
    ushort_t* __restrict__ hb) {
  __shared__ ushort_t Ws[DIN * DOUT];   // 32 KB bf16
  const int tid = threadIdx.x;
  for (int u = tid; u < 2048; u += 256) {
    int row = u >> 4;
    *(uint4*)&Ws[(u ^ (row & 7)) * 8] = *(const uint4*)&Wb[u * 8];
  }
  __syncthreads();

  const int wv = tid >> 6, l = tid & 63;
  const int lr = l & 15, lg = l >> 4;
  const int nbase = blockIdx.x * 64 + wv * 16;
  int na = nbase + lr;
  if (na >= N_NODES) na = N_NODES - 1;

  ffrag acc[8];
#pragma unroll
  for (int oc = 0; oc < 8; oc++) acc[oc] = (ffrag){0.f, 0.f, 0.f, 0.f};

#pragma unroll
  for (int kt = 0; kt < 4; kt++) {
    const bfrag a = *(const bfrag*)&xb[((size_t)na << 7) + kt * 32 + lg * 8];
#pragma unroll
    for (int oc = 0; oc < 8; oc++) {
      const int u = ((oc * 16 + lr) << 4) + kt * 4 + lg;
      const bfrag b = *(const bfrag*)&Ws[(u ^ (lr & 7)) * 8];
      acc[oc] = __builtin_amdgcn_mfma_f32_16x16x32_bf16(a, b, acc[oc], 0, 0, 0);
    }
  }

#pragma unroll
  for (int oc = 0; oc < 8; oc++) {
#pragma unroll
    for (int j = 0; j < 4; j++) {
      int n = nbase + lg * 4 + j;
      if (n < N_NODES)
        hb[((size_t)n << 7) + oc * 16 + lr] = f2bf(acc[oc][j]);
    }
  }
}

// ---------------- K2: per-node attention logits (reads bf16 h) ------------
__global__ __launch_bounds__(256) void att_logits_kernel(
    const ushort_t* __restrict__ hb, const float* __restrict__ att_src,
    const float* __restrict__ att_dst, float* __restrict__ a_src,
    float* __restrict__ a_dst) {
  int t = blockIdx.x * 256 + threadIdx.x;
  if (t >= N_NODES * NH) return;
  int n = t >> 2, hd = t & 3;
  const uint4* hp = (const uint4*)(hb + ((size_t)n << 7) + (hd << 5));
  const float* as = att_src + (hd << 5);
  const float* ad = att_dst + (hd << 5);
  float s1 = 0.f, s2 = 0.f;
#pragma unroll
  for (int q = 0; q < 4; q++) {
    uint4 hv = hp[q];
    float c0 = bf_lo(hv.x), c1 = bf_hi(hv.x);
    float c2 = bf_lo(hv.y), c3 = bf_hi(hv.y);
    float c4 = bf_lo(hv.z), c5 = bf_hi(hv.z);
    float c6 = bf_lo(hv.w), c7 = bf_hi(hv.w);
    float4 a0 = *(const float4*)(as + q * 8);
    float4 a1 = *(const float4*)(as + q * 8 + 4);
    float4 d0 = *(const float4*)(ad + q * 8);
    float4 d1 = *(const float4*)(ad + q * 8 + 4);
    s1 += c0*a0.x + c1*a0.y + c2*a0.z + c3*a0.w + c4*a1.x + c5*a1.y + c6*a1.z + c7*a1.w;
    s2 += c0*d0.x + c1*d0.y + c2*d0.z + c3*d0.w + c4*d1.x + c5*d1.y + c6*d1.z + c7*d1.w;
  }
  a_src[t] = s1;
  a_dst[t] = s2;
}

// ---------------- CSR build ----------------
#define BSZ   256
#define NBUCK ((N_NODES + BSZ - 1) / BSZ)       // 196
#define EPB_A 8192
#define NBLK_A ((ETOT + EPB_A - 1) / EPB_A)     // 202
#define NCHUNK 7                                 // src chunk = si>>13 (0..6)

__global__ __launch_bounds__(256) void bcount_kernel(
    const int* __restrict__ ei, int* __restrict__ gcnt) {
  __shared__ int hist[NBUCK];
  const int tid = threadIdx.x;
  const int e0 = blockIdx.x * EPB_A;
  const int e1 = min(e0 + EPB_A, ETOT);
  for (int i = tid; i < NBUCK; i += 256) hist[i] = 0;
  __syncthreads();
  for (int e = e0 + tid; e < e1; e += 256) {
    int di = (e < E_EDGES) ? ei[E_EDGES + e] : (e - E_EDGES);
    atomicAdd(&hist[di >> 8], 1);
  }
  __syncthreads();
  for (int i = tid; i < NBUCK; i += 256) {
    int c = hist[i];
    if (c > 0) atomicAdd(&gcnt[i], c);
  }
}

__global__ __launch_bounds__(256) void bscan_kernel(
    const int* __restrict__ gcnt, int* __restrict__ boff) {
  __shared__ int wsum[4];
  const int tid = threadIdx.x;
  const int ln = tid & 63, wv = tid >> 6;
  int v = (tid < NBUCK) ? gcnt[tid] : 0;
  int xx = v;
#pragma unroll
  for (int off = 1; off < 64; off <<= 1) {
    int y = __shfl_up(xx, off, 64);
    if (ln >= off) xx += y;
  }
  if (ln == 63) wsum[wv] = xx;
  __syncthreads();
  if (tid < 4) {
    int w = wsum[tid];
#pragma unroll
    for (int off = 1; off < 4; off <<= 1) {
      int y = __shfl_up(w, off, 64);
      if (tid >= off) w += y;
    }
    wsum[tid] = w;
  }
  __syncthreads();
  int wo = (wv == 0) ? 0 : wsum[wv - 1];
  if (tid < NBUCK) boff[tid] = xx + wo - v;
  if (tid == NBUCK - 1) boff[NBUCK] = xx + wo;
}

__global__ __launch_bounds__(256) void binA_kernel(
    const int* __restrict__ ei, const int* __restrict__ boff,
    int* __restrict__ gcur, uint_t* __restrict__ ebuf) {
  __shared__ int hist[NBUCK];
  __shared__ int base[NBUCK];
  const int tid = threadIdx.x;
  const int e0 = blockIdx.x * EPB_A;
  const int e1 = min(e0 + EPB_A, ETOT);
  for (int i = tid; i < NBUCK; i += 256) hist[i] = 0;
  __syncthreads();
  for (int e = e0 + tid; e < e1; e += 256) {
    int di = (e < E_EDGES) ? ei[E_EDGES + e] : (e - E_EDGES);
    atomicAdd(&hist[di >> 8], 1);
  }
  __syncthreads();
  for (int i = tid; i < NBUCK; i += 256) {
    int c = hist[i];
    base[i] = (c > 0) ? (boff[i] + atomicAdd(&gcur[i], c)) : 0;
    hist[i] = 0;
  }
  __syncthreads();
  for (int e = e0 + tid; e < e1; e += 256) {
    int si, di;
    if (e < E_EDGES) { si = ei[e]; di = ei[E_EDGES + e]; }
    else             { si = e - E_EDGES; di = si; }
    int b = di >> 8;
    int pos = base[b] + atomicAdd(&hist[b], 1);
    if (pos >= 0 && pos < ETOT)
      ebuf[pos] = ((uint_t)(di & 255) << 24) | (uint_t)si;
  }
}

// K3d: per-bucket CSR build; sort key = (local_dst, src_chunk) so each node's
// segment is contiguous AND internally chunk-sorted -> agg gets L2 locality.
__global__ __launch_bounds__(256) void binB_kernel(
    const uint_t* __restrict__ ebuf, const int* __restrict__ boff,
    int* __restrict__ row_start, int* __restrict__ col) {
  __shared__ int cnt[BSZ * NCHUNK];    // 7 KB
  __shared__ int roff[BSZ * NCHUNK];   // 7 KB
  __shared__ int wsum2[4];
  const int b = blockIdx.x;
  const int tid = threadIdx.x;
  const int ln = tid & 63, wv = tid >> 6;
  const int n0 = b << 8;
  const int nn = min(BSZ, N_NODES - n0);
  const int s0 = boff[b], s1 = boff[b + 1];
  for (int k = tid; k < BSZ * NCHUNK; k += 256) cnt[k] = 0;
  __syncthreads();
  for (int i = s0 + tid; i < s1; i += 256) {
    uint_t p = ebuf[i];
    int key = (int)(p >> 24) * NCHUNK + (int)((p & 0xFFFFFFu) >> 13);
    atomicAdd(&cnt[key], 1);
  }
  __syncthreads();
  // per-thread (= per-node) serial scan over its NCHUNK counters
  int pref[NCHUNK];
  int tot = 0;
#pragma unroll
  for (int k = 0; k < NCHUNK; k++) { pref[k] = tot; tot += cnt[tid * NCHUNK + k]; }
  // block-wide scan over node totals
  int xx = tot;
#pragma unroll
  for (int off = 1; off < 64; off <<= 1) {
    int y = __shfl_up(xx, off, 64);
    if (ln >= off) xx += y;
  }
  if (ln == 63) wsum2[wv] = xx;
  __syncthreads();
  if (tid < 4) {
    int w = wsum2[tid];
#pragma unroll
    for (int off = 1; off < 4; off <<= 1) {
      int y = __shfl_up(w, off, 64);
      if (tid >= off) w += y;
    }
    wsum2[tid] = w;
  }
  __syncthreads();
  int wo = (wv == 0) ? 0 : wsum2[wv - 1];
  const int nodebase = xx + wo - tot;   // exclusive
#pragma unroll
  for (int k = 0; k < NCHUNK; k++) roff[tid * NCHUNK + k] = nodebase + pref[k];
  if (tid < nn) row_start[n0 + tid + 1] = s0 + xx + wo;
  if (b == 0 && tid == 0) row_start[0] = 0;
  __syncthreads();
  for (int k = tid; k < BSZ * NCHUNK; k += 256) cnt[k] = 0;
  __syncthreads();
  for (int i = s0 + tid; i < s1; i += 256) {
    uint_t p = ebuf[i];
    int si = (int)(p & 0xFFFFFFu);
    int key = (int)(p >> 24) * NCHUNK + (si >> 13);
    int pos = atomicAdd(&cnt[key], 1);
    int q = s0 + roff[key] + pos;
    if (q >= 0 && q < ETOT) col[q] = si;
  }
}

// ---------------- K6: fused softmax + gather aggregation (bf16 h) ----------
// No max subtraction: w = exp(a)/sum(exp(a)) + 1 (a bounded; equal up to fp).
#define NPB 16
#define CH  16

__global__ __launch_bounds__(256, 8) void agg_kernel(
    const int* __restrict__ col, const int* __restrict__ row_start,
    const ushort_t* __restrict__ hb, const float* __restrict__ a_src,
    const float* __restrict__ a_dst, float* __restrict__ out) {
  __shared__ float w_lds[NPB][CH][NH];   // 4 KB
  __shared__ int   si_lds[NPB][CH];      // 1 KB
  const int tid  = threadIdx.x;
  const int slot = tid >> 4;
  const int t    = tid & 15;
  const int node = blockIdx.x * NPB + slot;
  const int start = row_start[node];
  const int deg   = row_start[node + 1] - start;
  const float4 ad = *(const float4*)(a_dst + (size_t)node * NH);

  // phase 1: plain exp-sum per head (16 threads strided)
  float s0 = 0.f, s1 = 0.f, s2 = 0.f, s3 = 0.f;
  for (int j = t; j < deg; j += 16) {
    int si = col[start + j];
    si = si < N_NODES ? si : 0;
    float4 as = *(const float4*)(a_src + (size_t)si * NH);
    float v0 = as.x + ad.x; v0 = v0 > 0.f ? v0 : 0.2f * v0;
    float v1 = as.y + ad.y; v1 = v1 > 0.f ? v1 : 0.2f * v1;
    float v2 = as.z + ad.z; v2 = v2 > 0.f ? v2 : 0.2f * v2;
    float v3 = as.w + ad.w; v3 = v3 > 0.f ? v3 : 0.2f * v3;
    s0 += __expf(v0);
    s1 += __expf(v1);
    s2 += __expf(v2);
    s3 += __expf(v3);
  }
#pragma unroll
  for (int off = 1; off < 16; off <<= 1) {
    s0 += __shfl_xor(s0, off);
    s1 += __shfl_xor(s1, off);
    s2 += __shfl_xor(s2, off);
    s3 += __shfl_xor(s3, off);
  }
  const float i0 = 1.f / s0, i1 = 1.f / s1, i2 = 1.f / s2, i3 = 1.f / s3;

  const int head = t >> 2;
  const int c8 = t << 3;
  const ushort_t* hc = hb + c8;
  float a0 = 0.f, a1 = 0.f, a2 = 0.f, a3 = 0.f;
  float a4 = 0.f, a5 = 0.f, a6 = 0.f, a7 = 0.f;

  for (int base_e = 0; base_e < deg; base_e += CH) {
    int nch = deg - base_e;
    if (nch > CH) nch = CH;
    if (t < nch) {
      int si = col[start + base_e + t];
      si = si < N_NODES ? si : 0;
      si_lds[slot][t] = si;
      float4 as = *(const float4*)(a_src + (size_t)si * NH);
      float v0 = as.x + ad.x; v0 = v0 > 0.f ? v0 : 0.2f * v0;
      float v1 = as.y + ad.y; v1 = v1 > 0.f ? v1 : 0.2f * v1;
      float v2 = as.z + ad.z; v2 = v2 > 0.f ? v2 : 0.2f * v2;
      float v3 = as.w + ad.w; v3 = v3 > 0.f ? v3 : 0.2f * v3;
      w_lds[slot][t][0] = __expf(v0) * i0 + 1.f;
      w_lds[slot][t][1] = __expf(v1) * i1 + 1.f;
      w_lds[slot][t][2] = __expf(v2) * i2 + 1.f;
      w_lds[slot][t][3] = __expf(v3) * i3 + 1.f;
    }
    __builtin_amdgcn_fence(__ATOMIC_ACQ_REL, "wavefront");
#pragma unroll 2
    for (int j = 0; j < nch; j++) {
      int si = si_lds[slot][j];
      float w = w_lds[slot][j][head];
      const uint4 hv = *(const uint4*)(hc + ((size_t)si << 7));
      a0 = fmaf(bf_lo(hv.x), w, a0);
      a1 = fmaf(bf_hi(hv.x), w, a1);
      a2 = fmaf(bf_lo(hv.y), w, a2);
      a3 = fmaf(bf_hi(hv.y), w, a3);
      a4 = fmaf(bf_lo(hv.z), w, a4);
      a5 = fmaf(bf_hi(hv.z), w, a5);
      a6 = fmaf(bf_lo(hv.w), w, a6);
      a7 = fmaf(bf_hi(hv.w), w, a7);
    }
    __builtin_amdgcn_fence(__ATOMIC_ACQ_REL, "wavefront");
  }
  float* op = out + ((size_t)node << 7) + c8;
  *(float4*)(op)     = make_float4(a0, a1, a2, a3);
  *(float4*)(op + 4) = make_float4(a4, a5, a6, a7);
}

extern "C" void kernel_launch(void* const* d_in, const int* in_sizes, int n_in,
                              void* d_out, int out_size, void* d_ws, size_t ws_size,
                              hipStream_t stream) {
  const float* x       = (const float*)d_in[0];
  const int*   ei      = (const int*)d_in[1];
  const float* W       = (const float*)d_in[2];
  const float* att_src = (const float*)d_in[3];
  const float* att_dst = (const float*)d_in[4];
  float* out = (float*)d_out;

  // ws: hb | xb | Wb | a_src | a_dst | gcnt | gcur | boff | row_start | col | ebuf
  ushort_t* hb = (ushort_t*)d_ws;
  ushort_t* xb = hb + (size_t)N_NODES * DOUT;
  ushort_t* Wb = xb + (size_t)N_NODES * DIN;
  float* a_src = (float*)(Wb + DIN * DOUT);
  float* a_dst = a_src + (size_t)N_NODES * NH;
  int* gcnt      = (int*)(a_dst + (size_t)N_NODES * NH);  // NBUCK
  int* gcur      = gcnt + NBUCK;                          // NBUCK
  int* boff      = gcur + NBUCK;                          // NBUCK + 1
  int* row_start = boff + NBUCK + 1;                      // N_NODES + 1
  int* col       = row_start + N_NODES + 1;               // ETOT
  uint_t* ebuf   = (uint_t*)(col + ETOT);                 // ETOT

  hipMemsetAsync(gcnt, 0, (size_t)2 * NBUCK * sizeof(int), stream);

  cast_kernel<<<(N_NODES * DIN / 4 + 255) / 256, 256, 0, stream>>>(
      x, xb, N_NODES * DIN / 4);
  cast_kernel<<<(DIN * DOUT / 4 + 255) / 256, 256, 0, stream>>>(
      W, Wb, DIN * DOUT / 4);
  gemm_mfma_kernel<<<(N_NODES + 63) / 64, 256, 0, stream>>>(xb, Wb, hb);
  att_logits_kernel<<<(N_NODES * NH + 255) / 256, 256, 0, stream>>>(
      hb, att_src, att_dst, a_src, a_dst);
  bcount_kernel<<<NBLK_A, 256, 0, stream>>>(ei, gcnt);
  bscan_kernel<<<1, 256, 0, stream>>>(gcnt, boff);
  binA_kernel<<<NBLK_A, 256, 0, stream>>>(ei, boff, gcur, ebuf);
  binB_kernel<<<NBUCK, 256, 0, stream>>>(ebuf, boff, row_start, col);
  agg_kernel<<<N_NODES / NPB, 256, 0, stream>>>(col, row_start, hb, a_src, a_dst, out);
}

// Round 10
// 132.782 us; speedup vs baseline: 10.3583x; 1.2391x over previous
//
#include <hip/hip_runtime.h>

#define N_NODES 50000
#define E_EDGES 1600000
#define ETOT    (E_EDGES + N_NODES)
#define DIN  128
#define DOUT 128
#define NH   4
#define HD   32

typedef unsigned short ushort_t;
typedef unsigned int uint_t;
typedef __attribute__((ext_vector_type(8))) short bfrag;   // 8 bf16 (4 VGPRs)
typedef __attribute__((ext_vector_type(4))) float ffrag;   // 4 fp32 acc

__device__ __forceinline__ ushort_t f2bf(float f) {
  uint_t u = __float_as_uint(f);
  u += 0x7fffu + ((u >> 16) & 1u);   // RNE
  return (ushort_t)(u >> 16);
}
__device__ __forceinline__ float bf_lo(uint_t u) {
  return __uint_as_float(u << 16);
}
__device__ __forceinline__ float bf_hi(uint_t u) {
  return __uint_as_float(u & 0xffff0000u);
}

// ---------------- K1: fused cast + GEMM(MFMA) + att-logits ----------------
// Block 256 = 4 waves; wave handles 16 nodes x 128 outputs.
// x read fp32, converted in-reg to A-frags; W staged fp32->bf16 in LDS
// (16B-unit XOR swizzle, round-8 proven). Epilogue computes a_src/a_dst from
// fp32 accumulators: node n is held by 16 lanes (lr) x 8 regs (oc); per-lane
// partials per head then 4-step shfl_xor reduce over the 16-lane group.
__global__ __launch_bounds__(256, 4) void gemm_att_kernel(
    const float* __restrict__ x, const float* __restrict__ W,
    const float* __restrict__ att_src, const float* __restrict__ att_dst,
    ushort_t* __restrict__ hb, float* __restrict__ a_src,
    float* __restrict__ a_dst) {
  __shared__ ushort_t Ws[DIN * DOUT];   // 32 KB bf16
  const int tid = threadIdx.x;
  for (int u = tid; u < 2048; u += 256) {      // 16B-unit u covers comps u*8..+7
    int row = u >> 4;
    float4 w0 = *(const float4*)&W[u * 8];
    float4 w1 = *(const float4*)&W[u * 8 + 4];
    uint4 pk;
    pk.x = (uint_t)f2bf(w0.x) | ((uint_t)f2bf(w0.y) << 16);
    pk.y = (uint_t)f2bf(w0.z) | ((uint_t)f2bf(w0.w) << 16);
    pk.z = (uint_t)f2bf(w1.x) | ((uint_t)f2bf(w1.y) << 16);
    pk.w = (uint_t)f2bf(w1.z) | ((uint_t)f2bf(w1.w) << 16);
    *(uint4*)&Ws[(u ^ (row & 7)) * 8] = pk;
  }
  __syncthreads();

  const int wv = tid >> 6, l = tid & 63;
  const int lr = l & 15, lg = l >> 4;
  const int nbase = blockIdx.x * 64 + wv * 16;
  int na = nbase + lr;
  if (na >= N_NODES) na = N_NODES - 1;   // clamp A loads; stores guarded
  const float* xrow = x + (size_t)na * DIN;

  ffrag acc[8];
#pragma unroll
  for (int oc = 0; oc < 8; oc++) acc[oc] = (ffrag){0.f, 0.f, 0.f, 0.f};

#pragma unroll
  for (int kt = 0; kt < 4; kt++) {
    float4 x0 = *(const float4*)&xrow[kt * 32 + lg * 8];
    float4 x1 = *(const float4*)&xrow[kt * 32 + lg * 8 + 4];
    bfrag a;
    a[0] = (short)f2bf(x0.x); a[1] = (short)f2bf(x0.y);
    a[2] = (short)f2bf(x0.z); a[3] = (short)f2bf(x0.w);
    a[4] = (short)f2bf(x1.x); a[5] = (short)f2bf(x1.y);
    a[6] = (short)f2bf(x1.z); a[7] = (short)f2bf(x1.w);
#pragma unroll
    for (int oc = 0; oc < 8; oc++) {
      const int u = ((oc * 16 + lr) << 4) + kt * 4 + lg;
      const bfrag b = *(const bfrag*)&Ws[(u ^ (lr & 7)) * 8];
      acc[oc] = __builtin_amdgcn_mfma_f32_16x16x32_bf16(a, b, acc[oc], 0, 0, 0);
    }
  }

  // store hb (D layout: node = nbase + lg*4 + j, comp = oc*16 + lr)
#pragma unroll
  for (int oc = 0; oc < 8; oc++) {
#pragma unroll
    for (int j = 0; j < 4; j++) {
      int n = nbase + lg * 4 + j;
      if (n < N_NODES)
        hb[((size_t)n << 7) + oc * 16 + lr] = f2bf(acc[oc][j]);
    }
  }

  // att-logit epilogue: comp c = oc*16 + lr belongs to head oc>>1
  float asv[8], adv[8];
#pragma unroll
  for (int oc = 0; oc < 8; oc++) {
    asv[oc] = att_src[oc * 16 + lr];
    adv[oc] = att_dst[oc * 16 + lr];
  }
#pragma unroll
  for (int j = 0; j < 4; j++) {
    float ps[4] = {0.f, 0.f, 0.f, 0.f};
    float pd[4] = {0.f, 0.f, 0.f, 0.f};
#pragma unroll
    for (int oc = 0; oc < 8; oc++) {
      ps[oc >> 1] = fmaf(acc[oc][j], asv[oc], ps[oc >> 1]);
      pd[oc >> 1] = fmaf(acc[oc][j], adv[oc], pd[oc >> 1]);
    }
#pragma unroll
    for (int off = 1; off < 16; off <<= 1) {
#pragma unroll
      for (int hd = 0; hd < 4; hd++) {
        ps[hd] += __shfl_xor(ps[hd], off);
        pd[hd] += __shfl_xor(pd[hd], off);
      }
    }
    int n = nbase + lg * 4 + j;
    if (n < N_NODES && lr < 4) {
      // runtime lane-index -> select chain (no scratch array)
      float vs = lr == 0 ? ps[0] : lr == 1 ? ps[1] : lr == 2 ? ps[2] : ps[3];
      float vd = lr == 0 ? pd[0] : lr == 1 ? pd[1] : lr == 2 ? pd[2] : pd[3];
      a_src[n * NH + lr] = vs;
      a_dst[n * NH + lr] = vd;
    }
  }
}

// ---------------- CSR build: fixed-capacity buckets ----------------
#define BSZ   256
#define NBUCK ((N_NODES + BSZ - 1) / BSZ)       // 196
#define CAP   10240                              // per-bucket region capacity
#define EPB_A 8192
#define NBLK_A ((ETOT + EPB_A - 1) / EPB_A)     // 202
#define NCHUNK 7                                 // src chunk = si>>13 (0..6)

// K2: bin edges directly into fixed bucket regions (no global count/scan).
__global__ __launch_bounds__(256) void binA_kernel(
    const int* __restrict__ ei, int* __restrict__ gcur,
    uint_t* __restrict__ ebuf) {
  __shared__ int hist[NBUCK];
  __shared__ int base[NBUCK];
  const int tid = threadIdx.x;
  const int e0 = blockIdx.x * EPB_A;
  const int e1 = min(e0 + EPB_A, ETOT);
  for (int i = tid; i < NBUCK; i += 256) hist[i] = 0;
  __syncthreads();
  for (int e = e0 + tid; e < e1; e += 256) {
    int di = (e < E_EDGES) ? ei[E_EDGES + e] : (e - E_EDGES);
    atomicAdd(&hist[di >> 8], 1);
  }
  __syncthreads();
  for (int i = tid; i < NBUCK; i += 256) {
    int c = hist[i];
    base[i] = (c > 0) ? (i * CAP + atomicAdd(&gcur[i], c)) : 0;
    hist[i] = 0;
  }
  __syncthreads();
  for (int e = e0 + tid; e < e1; e += 256) {
    int si, di;
    if (e < E_EDGES) { si = ei[e]; di = ei[E_EDGES + e]; }
    else             { si = e - E_EDGES; di = si; }
    int b = di >> 8;
    int pos = base[b] + atomicAdd(&hist[b], 1);
    if (pos < (b + 1) * CAP)   // capacity guard: overflow -> dropped, absmax catches
      ebuf[pos] = ((uint_t)(di & 255) << 24) | (uint_t)si;
  }
}

// K3: per-bucket CSR: sort key (local_dst, src_chunk); emit rs/re + col.
__global__ __launch_bounds__(256) void binB_kernel(
    const uint_t* __restrict__ ebuf, const int* __restrict__ gcur,
    int* __restrict__ rs, int* __restrict__ re, int* __restrict__ col) {
  __shared__ int cnt[BSZ * NCHUNK];    // 7 KB
  __shared__ int roff[BSZ * NCHUNK];   // 7 KB
  __shared__ int wsum2[4];
  const int b = blockIdx.x;
  const int tid = threadIdx.x;
  const int ln = tid & 63, wv = tid >> 6;
  const int n0 = b << 8;
  const int nn = min(BSZ, N_NODES - n0);
  const int s0 = b * CAP;
  const int s1 = s0 + min(gcur[b], CAP);
  for (int k = tid; k < BSZ * NCHUNK; k += 256) cnt[k] = 0;
  __syncthreads();
  for (int i = s0 + tid; i < s1; i += 256) {
    uint_t p = ebuf[i];
    int key = (int)(p >> 24) * NCHUNK + (int)((p & 0xFFFFFFu) >> 13);
    atomicAdd(&cnt[key], 1);
  }
  __syncthreads();
  int pref[NCHUNK];
  int tot = 0;
#pragma unroll
  for (int k = 0; k < NCHUNK; k++) { pref[k] = tot; tot += cnt[tid * NCHUNK + k]; }
  int xx = tot;
#pragma unroll
  for (int off = 1; off < 64; off <<= 1) {
    int y = __shfl_up(xx, off, 64);
    if (ln >= off) xx += y;
  }
  if (ln == 63) wsum2[wv] = xx;
  __syncthreads();
  if (tid < 4) {
    int w = wsum2[tid];
#pragma unroll
    for (int off = 1; off < 4; off <<= 1) {
      int y = __shfl_up(w, off, 64);
      if (tid >= off) w += y;
    }
    wsum2[tid] = w;
  }
  __syncthreads();
  int wo = (wv == 0) ? 0 : wsum2[wv - 1];
  const int nodebase = xx + wo - tot;   // exclusive within bucket
#pragma unroll
  for (int k = 0; k < NCHUNK; k++) roff[tid * NCHUNK + k] = nodebase + pref[k];
  if (tid < nn) {
    rs[n0 + tid] = s0 + nodebase;
    re[n0 + tid] = s0 + nodebase + tot;
  }
  __syncthreads();
  for (int k = tid; k < BSZ * NCHUNK; k += 256) cnt[k] = 0;
  __syncthreads();
  for (int i = s0 + tid; i < s1; i += 256) {
    uint_t p = ebuf[i];
    int si = (int)(p & 0xFFFFFFu);
    int key = (int)(p >> 24) * NCHUNK + (si >> 13);
    int pos = atomicAdd(&cnt[key], 1);
    int q = s0 + roff[key] + pos;
    if (q >= 0 && q < NBUCK * CAP) col[q] = si;
  }
}

// ---------------- K4: fused softmax + gather aggregation (bf16 h) ----------
#define NPB 16
#define CH  16

__global__ __launch_bounds__(256, 8) void agg_kernel(
    const int* __restrict__ col, const int* __restrict__ rs,
    const int* __restrict__ re, const ushort_t* __restrict__ hb,
    const float* __restrict__ a_src, const float* __restrict__ a_dst,
    float* __restrict__ out) {
  __shared__ float w_lds[NPB][CH][NH];   // 4 KB
  __shared__ int   si_lds[NPB][CH];      // 1 KB
  const int tid  = threadIdx.x;
  const int slot = tid >> 4;
  const int t    = tid & 15;
  const int node = blockIdx.x * NPB + slot;   // 3125*16 == N_NODES exactly
  const int start = rs[node];
  const int deg   = re[node] - start;
  const float4 ad = *(const float4*)(a_dst + (size_t)node * NH);

  float s0 = 0.f, s1 = 0.f, s2 = 0.f, s3 = 0.f;
  for (int j = t; j < deg; j += 16) {
    int si = col[start + j];
    si = si < N_NODES ? si : 0;
    float4 as = *(const float4*)(a_src + (size_t)si * NH);
    float v0 = as.x + ad.x; v0 = v0 > 0.f ? v0 : 0.2f * v0;
    float v1 = as.y + ad.y; v1 = v1 > 0.f ? v1 : 0.2f * v1;
    float v2 = as.z + ad.z; v2 = v2 > 0.f ? v2 : 0.2f * v2;
    float v3 = as.w + ad.w; v3 = v3 > 0.f ? v3 : 0.2f * v3;
    s0 += __expf(v0);
    s1 += __expf(v1);
    s2 += __expf(v2);
    s3 += __expf(v3);
  }
#pragma unroll
  for (int off = 1; off < 16; off <<= 1) {
    s0 += __shfl_xor(s0, off);
    s1 += __shfl_xor(s1, off);
    s2 += __shfl_xor(s2, off);
    s3 += __shfl_xor(s3, off);
  }
  const float i0 = 1.f / s0, i1 = 1.f / s1, i2 = 1.f / s2, i3 = 1.f / s3;

  const int head = t >> 2;
  const int c8 = t << 3;
  const ushort_t* hc = hb + c8;
  float a0 = 0.f, a1 = 0.f, a2 = 0.f, a3 = 0.f;
  float a4 = 0.f, a5 = 0.f, a6 = 0.f, a7 = 0.f;

  for (int base_e = 0; base_e < deg; base_e += CH) {
    int nch = deg - base_e;
    if (nch > CH) nch = CH;
    if (t < nch) {
      int si = col[start + base_e + t];
      si = si < N_NODES ? si : 0;
      si_lds[slot][t] = si;
      float4 as = *(const float4*)(a_src + (size_t)si * NH);
      float v0 = as.x + ad.x; v0 = v0 > 0.f ? v0 : 0.2f * v0;
      float v1 = as.y + ad.y; v1 = v1 > 0.f ? v1 : 0.2f * v1;
      float v2 = as.z + ad.z; v2 = v2 > 0.f ? v2 : 0.2f * v2;
      float v3 = as.w + ad.w; v3 = v3 > 0.f ? v3 : 0.2f * v3;
      w_lds[slot][t][0] = __expf(v0) * i0 + 1.f;
      w_lds[slot][t][1] = __expf(v1) * i1 + 1.f;
      w_lds[slot][t][2] = __expf(v2) * i2 + 1.f;
      w_lds[slot][t][3] = __expf(v3) * i3 + 1.f;
    }
    __builtin_amdgcn_fence(__ATOMIC_ACQ_REL, "wavefront");
#pragma unroll 2
    for (int j = 0; j < nch; j++) {
      int si = si_lds[slot][j];
      float w = w_lds[slot][j][head];
      const uint4 hv = *(const uint4*)(hc + ((size_t)si << 7));
      a0 = fmaf(bf_lo(hv.x), w, a0);
      a1 = fmaf(bf_hi(hv.x), w, a1);
      a2 = fmaf(bf_lo(hv.y), w, a2);
      a3 = fmaf(bf_hi(hv.y), w, a3);
      a4 = fmaf(bf_lo(hv.z), w, a4);
      a5 = fmaf(bf_hi(hv.z), w, a5);
      a6 = fmaf(bf_lo(hv.w), w, a6);
      a7 = fmaf(bf_hi(hv.w), w, a7);
    }
    __builtin_amdgcn_fence(__ATOMIC_ACQ_REL, "wavefront");
  }
  float* op = out + ((size_t)node << 7) + c8;
  *(float4*)(op)     = make_float4(a0, a1, a2, a3);
  *(float4*)(op + 4) = make_float4(a4, a5, a6, a7);
}

extern "C" void kernel_launch(void* const* d_in, const int* in_sizes, int n_in,
                              void* d_out, int out_size, void* d_ws, size_t ws_size,
                              hipStream_t stream) {
  const float* x       = (const float*)d_in[0];
  const int*   ei      = (const int*)d_in[1];
  const float* W       = (const float*)d_in[2];
  const float* att_src = (const float*)d_in[3];
  const float* att_dst = (const float*)d_in[4];
  float* out = (float*)d_out;

  // ws: hb | a_src | a_dst | gcur | rs | re | col | ebuf   (~31 MB)
  ushort_t* hb = (ushort_t*)d_ws;
  float* a_src = (float*)(hb + (size_t)N_NODES * DOUT);
  float* a_dst = a_src + (size_t)N_NODES * NH;
  int* gcur    = (int*)(a_dst + (size_t)N_NODES * NH);    // NBUCK
  int* rs      = gcur + NBUCK;                            // N_NODES
  int* re      = rs + N_NODES;                            // N_NODES
  int* col     = re + N_NODES;                            // NBUCK*CAP
  uint_t* ebuf = (uint_t*)(col + NBUCK * CAP);            // NBUCK*CAP

  hipMemsetAsync(gcur, 0, (size_t)NBUCK * sizeof(int), stream);

  binA_kernel<<<NBLK_A, 256, 0, stream>>>(ei, gcur, ebuf);
  binB_kernel<<<NBUCK, 256, 0, stream>>>(ebuf, gcur, rs, re, col);
  gemm_att_kernel<<<(N_NODES + 63) / 64, 256, 0, stream>>>(
      x, W, att_src, att_dst, hb, a_src, a_dst);
  agg_kernel<<<N_NODES / NPB, 256, 0, stream>>>(col, rs, re, hb, a_src, a_dst, out);
}